// Round 5
// baseline (417.532 us; speedup 1.0000x reference)
//
#include <hip/hip_runtime.h>
#include <math.h>

#define N_NODES 100000
#define N_EDGES 1600000
#define NBLK_N 391   // ceil(N/256)
#define NB     391   // buckets of 256 nodes
#define CHUNK  4096  // edges per k_bin block
#define NBLK_A 391   // ceil(E/CHUNK)

typedef unsigned short ushort_t;

__device__ inline unsigned short f2bf(float f) {
    unsigned u = __float_as_uint(f);
    unsigned r = (u + 0x7FFFu + ((u >> 16) & 1u)) >> 16;
    return (unsigned short)r;
}
// accumulate 2 packed bf16 (little-endian: lo=bits[15:0]) into 2 fp32
__device__ inline void acc2(float& a0, float& a1, unsigned u) {
    a0 += __uint_as_float(u << 16);
    a1 += __uint_as_float(u & 0xFFFF0000u);
}

// ---------------- degree + rowptr ----------------

__global__ __launch_bounds__(256) void k_zero_u32(unsigned* __restrict__ p, int n) {
    int i = blockIdx.x * 256 + threadIdx.x;
    if (i < n) p[i] = 0u;
}

__global__ __launch_bounds__(256) void k_hist(const int* __restrict__ dst,
                                              unsigned* __restrict__ hist) {
    int e = blockIdx.x * 256 + threadIdx.x;
    if (e < N_EDGES) atomicAdd(&hist[dst[e]], 1u);
}

__global__ __launch_bounds__(256) void k_blocksum(const unsigned* __restrict__ hist,
                                                  unsigned* __restrict__ bs) {
    __shared__ unsigned s[256];
    int i = blockIdx.x * 256 + threadIdx.x;
    unsigned v = (i < N_NODES) ? hist[i] : 0u;
    s[threadIdx.x] = v;
    __syncthreads();
    for (int o = 128; o > 0; o >>= 1) {
        if (threadIdx.x < o) s[threadIdx.x] += s[threadIdx.x + o];
        __syncthreads();
    }
    if (threadIdx.x == 0) bs[blockIdx.x] = s[0];
}

__global__ __launch_bounds__(512) void k_scanbs(unsigned* __restrict__ bs) {
    __shared__ unsigned s[512];
    int tid = threadIdx.x;
    unsigned v = (tid < NBLK_N) ? bs[tid] : 0u;
    s[tid] = v;
    __syncthreads();
    for (int o = 1; o < 512; o <<= 1) {
        unsigned t = (tid >= o) ? s[tid - o] : 0u;
        __syncthreads();
        s[tid] += t;
        __syncthreads();
    }
    if (tid < NBLK_N) bs[tid] = s[tid] - v;   // exclusive
}

__global__ __launch_bounds__(256) void k_scan_final(const unsigned* __restrict__ hist,
                                                    const unsigned* __restrict__ bs,
                                                    unsigned* __restrict__ rowptr,
                                                    float* __restrict__ dinv) {
    __shared__ unsigned s[256];
    int tid = threadIdx.x;
    int i = blockIdx.x * 256 + tid;
    unsigned v = (i < N_NODES) ? hist[i] : 0u;
    s[tid] = v;
    __syncthreads();
    for (int o = 1; o < 256; o <<= 1) {
        unsigned t = (tid >= o) ? s[tid - o] : 0u;
        __syncthreads();
        s[tid] += t;
        __syncthreads();
    }
    unsigned excl = s[tid] - v + bs[blockIdx.x];
    if (i < N_NODES) {
        rowptr[i] = excl;
        dinv[i] = rsqrtf((float)(v + 1u));
        if (i == N_NODES - 1) rowptr[N_NODES] = excl + v;  // == E
    }
}

__global__ __launch_bounds__(256) void k_init_bcur(const unsigned* __restrict__ rowptr,
                                                   unsigned* __restrict__ gbcur) {
    int t = blockIdx.x * 256 + threadIdx.x;
    if (t < NB) gbcur[t] = rowptr[t * 256];
}

// ---------------- phase A: LDS multisplit into 391 buckets ----------------
__global__ __launch_bounds__(256) void k_bin(const int* __restrict__ src,
                                             const int* __restrict__ dst,
                                             unsigned* __restrict__ gbcur,
                                             unsigned* __restrict__ binned) {
    __shared__ unsigned cntA[NB];
    __shared__ unsigned excl[NB];
    __shared__ unsigned gbase[NB];
    __shared__ unsigned scanbuf[512];
    __shared__ unsigned data[CHUNK];
    const int tid = threadIdx.x;
    const long e0 = (long)blockIdx.x * CHUNK;

    for (int i = tid; i < NB; i += 256) cntA[i] = 0u;
    __syncthreads();
    for (int i = tid; i < CHUNK; i += 256) {
        long e = e0 + i;
        if (e < N_EDGES) atomicAdd(&cntA[((unsigned)dst[e]) >> 8], 1u);
    }
    __syncthreads();
    scanbuf[tid] = (tid < NB) ? cntA[tid] : 0u;
    scanbuf[tid + 256] = (tid + 256 < NB) ? cntA[tid + 256] : 0u;
    __syncthreads();
    for (int o = 1; o < 512; o <<= 1) {
        unsigned v0 = (tid >= o) ? scanbuf[tid - o] : 0u;
        unsigned v1 = (tid + 256 >= o) ? scanbuf[tid + 256 - o] : 0u;
        __syncthreads();
        scanbuf[tid] += v0;
        scanbuf[tid + 256] += v1;
        __syncthreads();
    }
    for (int b = tid; b < NB; b += 256) {
        unsigned c = cntA[b];
        excl[b] = scanbuf[b] - c;
        gbase[b] = c ? atomicAdd(&gbcur[b], c) : 0u;
    }
    __syncthreads();
    for (int i = tid; i < NB; i += 256) cntA[i] = 0u;
    __syncthreads();
    for (int i = tid; i < CHUNK; i += 256) {
        long e = e0 + i;
        if (e < N_EDGES) {
            unsigned d = (unsigned)dst[e];
            unsigned b = d >> 8;
            unsigned slot = excl[b] + atomicAdd(&cntA[b], 1u);
            data[slot] = (((unsigned)src[e]) << 8) | (d & 255u);
        }
    }
    __syncthreads();
    const int w = tid >> 6, lane = tid & 63;
    for (int b = w; b < NB; b += 4) {
        unsigned c = cntA[b];
        unsigned sb = excl[b], gb = gbase[b];
        for (unsigned k = lane; k < c; k += 64)
            binned[gb + k] = data[sb + k];
    }
}

// ---------------- phase B: per-bucket CSR fill (LDS cursors) ----------------
__global__ __launch_bounds__(256) void k_csr_fill(const unsigned* __restrict__ binned,
                                                  const unsigned* __restrict__ rowptr,
                                                  int* __restrict__ ssrc) {
    __shared__ unsigned cur[256];
    const int b = blockIdx.x;
    const int tid = threadIdx.x;
    const int n0 = b * 256;
    const int n1 = (n0 + 256 < N_NODES) ? n0 + 256 : N_NODES;
    if (tid < n1 - n0) cur[tid] = rowptr[n0 + tid];
    __syncthreads();
    const unsigned beg = rowptr[n0], end = rowptr[n1];
    for (unsigned i = beg + tid; i < end; i += 256) {
        unsigned p = binned[i];
        unsigned pos = atomicAdd(&cur[p & 255u], 1u);
        ssrc[pos] = (int)(p >> 8);
    }
}

// ---------------- dense layers ----------------

// xlb[N x OUT] (bf16) = (A[N x K] @ W[K x OUT]) * dinv[row]
template<int K, int OUT>
__global__ __launch_bounds__(256) void k_gemm_bf(const float* __restrict__ A,
                                                 const float* __restrict__ W,
                                                 const float* __restrict__ dinv,
                                                 ushort_t* __restrict__ C) {
    constexpr int BR = 32;
    __shared__ float Wld[K * OUT];
    __shared__ float Ald[BR * K];
    const int tid = threadIdx.x;
    for (int i = tid; i < K * OUT; i += 256) Wld[i] = W[i];
    const long row0 = (long)blockIdx.x * BR;
    const float4* A4 = reinterpret_cast<const float4*>(A + row0 * K);
    float4* Ald4w = reinterpret_cast<float4*>(Ald);
    constexpr int NV = BR * K / 4;
    for (int i = tid; i < NV; i += 256) Ald4w[i] = A4[i];
    __syncthreads();

    constexpr int RG = 256 / OUT;
    constexpr int RPT = BR / RG;
    const int col = tid % OUT;
    const int rg = tid / OUT;
    const float4* Ald4 = reinterpret_cast<const float4*>(Ald);
    float acc[RPT];
#pragma unroll
    for (int j = 0; j < RPT; ++j) acc[j] = 0.f;
    for (int k4 = 0; k4 < K; k4 += 4) {
        const float w0 = Wld[(k4 + 0) * OUT + col];
        const float w1 = Wld[(k4 + 1) * OUT + col];
        const float w2 = Wld[(k4 + 2) * OUT + col];
        const float w3 = Wld[(k4 + 3) * OUT + col];
#pragma unroll
        for (int j = 0; j < RPT; ++j) {
            const float4 a = Ald4[((rg + j * RG) * K + k4) >> 2];
            acc[j] = fmaf(a.x, w0, fmaf(a.y, w1, fmaf(a.z, w2, fmaf(a.w, w3, acc[j]))));
        }
    }
#pragma unroll
    for (int j = 0; j < RPT; ++j) {
        const long r = row0 + rg + j * RG;
        C[r * OUT + col] = f2bf(acc[j] * dinv[r]);
    }
}

// one node per 64-lane wave; 8 lane-groups x 8 lanes; lane loads uint4 = 8 bf16.
// 16 edge-gathers in flight per wave (8 groups x unroll 2).
__global__ __launch_bounds__(256) void k_agg(const ushort_t* __restrict__ xlb,
                                             const float* __restrict__ dinv,
                                             const unsigned* __restrict__ rowptr,
                                             const int* __restrict__ ssrc,
                                             const float* __restrict__ bias,
                                             float* __restrict__ h) {
    const int node = blockIdx.x * 4 + (threadIdx.x >> 6);
    const int lane = threadIdx.x & 63;
    const int g = lane >> 3;        // edge group 0..7
    const int l = lane & 7;         // feature octet 0..7 (features l*8..l*8+7)
    const uint4* xb4 = reinterpret_cast<const uint4*>(xlb);  // 8 uint4 per row

    const unsigned beg = rowptr[node], end = rowptr[node + 1];
    float a[8] = {0.f,0.f,0.f,0.f,0.f,0.f,0.f,0.f};
    float b[8] = {0.f,0.f,0.f,0.f,0.f,0.f,0.f,0.f};
    if (g == 0) {   // self-loop
        const uint4 v = xb4[(size_t)node * 8 + l];
        acc2(a[0], a[1], v.x); acc2(a[2], a[3], v.y);
        acc2(a[4], a[5], v.z); acc2(a[6], a[7], v.w);
    }
    unsigned j = beg + g;
    for (; j + 8 < end; j += 16) {
        const int s0 = ssrc[j];
        const int s1 = ssrc[j + 8];
        const uint4 v0 = xb4[(size_t)s0 * 8 + l];
        const uint4 v1 = xb4[(size_t)s1 * 8 + l];
        acc2(a[0], a[1], v0.x); acc2(a[2], a[3], v0.y);
        acc2(a[4], a[5], v0.z); acc2(a[6], a[7], v0.w);
        acc2(b[0], b[1], v1.x); acc2(b[2], b[3], v1.y);
        acc2(b[4], b[5], v1.z); acc2(b[6], b[7], v1.w);
    }
    if (j < end) {
        const uint4 v = xb4[(size_t)ssrc[j] * 8 + l];
        acc2(a[0], a[1], v.x); acc2(a[2], a[3], v.y);
        acc2(a[4], a[5], v.z); acc2(a[6], a[7], v.w);
    }
#pragma unroll
    for (int i = 0; i < 8; ++i) a[i] += b[i];
#pragma unroll
    for (int i = 0; i < 8; ++i) {
        a[i] += __shfl_xor(a[i], 8);
        a[i] += __shfl_xor(a[i], 16);
        a[i] += __shfl_xor(a[i], 32);
    }
    if (g == 0) {
        const float di = dinv[node];
        const float4 b0 = reinterpret_cast<const float4*>(bias)[l * 2];
        const float4 b1 = reinterpret_cast<const float4*>(bias)[l * 2 + 1];
        float4 r0, r1;
        r0.x = tanhf(fmaf(a[0], di, b0.x));
        r0.y = tanhf(fmaf(a[1], di, b0.y));
        r0.z = tanhf(fmaf(a[2], di, b0.z));
        r0.w = tanhf(fmaf(a[3], di, b0.w));
        r1.x = tanhf(fmaf(a[4], di, b1.x));
        r1.y = tanhf(fmaf(a[5], di, b1.y));
        r1.z = tanhf(fmaf(a[6], di, b1.z));
        r1.w = tanhf(fmaf(a[7], di, b1.w));
        float4* hp = reinterpret_cast<float4*>(h) + (size_t)node * 16 + l * 2;
        hp[0] = r0;
        hp[1] = r1;
    }
}

// fused FC stack, register-tiled fp32.
// fc0: 2 rows x 4 cols per thread, k unrolled x4 (float4 LDS reads).
// Hin/Ht padded to 68 floats/row -> row-group addresses hit banks {0,8,16,24}.
__global__ __launch_bounds__(256) void k_fc(const float* __restrict__ h2,
                                            const float* __restrict__ fW0, const float* __restrict__ fb0,
                                            const float* __restrict__ fW1, const float* __restrict__ fb1,
                                            const float* __restrict__ fW2, const float* __restrict__ fb2,
                                            float* __restrict__ out) {
    constexpr int BR = 32;
    constexpr int LDH = 68;
    __shared__ float W0[64 * 64];
    __shared__ float W1[64 * 32];
    __shared__ float Hin[BR * LDH];
    __shared__ float Ht[BR * LDH];
    __shared__ float Hs[BR * 33];
    __shared__ float W2s[33];
    const int tid = threadIdx.x;
    {
        const float4* w04 = reinterpret_cast<const float4*>(fW0);
        float4* W04 = reinterpret_cast<float4*>(W0);
        for (int i = tid; i < 64 * 16; i += 256) W04[i] = w04[i];
        const float4* w14 = reinterpret_cast<const float4*>(fW1);
        float4* W14 = reinterpret_cast<float4*>(W1);
        for (int i = tid; i < 64 * 8; i += 256) W14[i] = w14[i];
        if (tid < 32) W2s[tid] = fW2[tid];
        if (tid == 32) W2s[32] = fb2[0];
    }
    const long row0 = (long)blockIdx.x * BR;
    {
        const float4* H4 = reinterpret_cast<const float4*>(h2 + row0 * 64);
        for (int i = tid; i < BR * 16; i += 256) {
            int r = i >> 4, q = i & 15;
            *reinterpret_cast<float4*>(&Hin[r * LDH + q * 4]) = H4[i];
        }
    }
    __syncthreads();

    // ---- fc0: 32x64, tile 2x4, 256 threads ----
    {
        const int rp = tid >> 4;          // 0..15 -> rows 2rp, 2rp+1
        const int cq = tid & 15;          // cols 4cq..4cq+3
        const int r0 = rp * 2, r1 = r0 + 1;
        const float4 bias = reinterpret_cast<const float4*>(fb0)[cq];
        float4 acc0 = bias, acc1 = bias;
        for (int k4 = 0; k4 < 64; k4 += 4) {
            const float4 a0 = *reinterpret_cast<const float4*>(&Hin[r0 * LDH + k4]);
            const float4 a1 = *reinterpret_cast<const float4*>(&Hin[r1 * LDH + k4]);
            const float4 w0 = *reinterpret_cast<const float4*>(&W0[(k4 + 0) * 64 + cq * 4]);
            const float4 w1 = *reinterpret_cast<const float4*>(&W0[(k4 + 1) * 64 + cq * 4]);
            const float4 w2 = *reinterpret_cast<const float4*>(&W0[(k4 + 2) * 64 + cq * 4]);
            const float4 w3 = *reinterpret_cast<const float4*>(&W0[(k4 + 3) * 64 + cq * 4]);
            acc0.x = fmaf(a0.x, w0.x, fmaf(a0.y, w1.x, fmaf(a0.z, w2.x, fmaf(a0.w, w3.x, acc0.x))));
            acc0.y = fmaf(a0.x, w0.y, fmaf(a0.y, w1.y, fmaf(a0.z, w2.y, fmaf(a0.w, w3.y, acc0.y))));
            acc0.z = fmaf(a0.x, w0.z, fmaf(a0.y, w1.z, fmaf(a0.z, w2.z, fmaf(a0.w, w3.z, acc0.z))));
            acc0.w = fmaf(a0.x, w0.w, fmaf(a0.y, w1.w, fmaf(a0.z, w2.w, fmaf(a0.w, w3.w, acc0.w))));
            acc1.x = fmaf(a1.x, w0.x, fmaf(a1.y, w1.x, fmaf(a1.z, w2.x, fmaf(a1.w, w3.x, acc1.x))));
            acc1.y = fmaf(a1.x, w0.y, fmaf(a1.y, w1.y, fmaf(a1.z, w2.y, fmaf(a1.w, w3.y, acc1.y))));
            acc1.z = fmaf(a1.x, w0.z, fmaf(a1.y, w1.z, fmaf(a1.z, w2.z, fmaf(a1.w, w3.z, acc1.z))));
            acc1.w = fmaf(a1.x, w0.w, fmaf(a1.y, w1.w, fmaf(a1.z, w2.w, fmaf(a1.w, w3.w, acc1.w))));
        }
        float4 t0, t1;
        t0.x = tanhf(acc0.x); t0.y = tanhf(acc0.y); t0.z = tanhf(acc0.z); t0.w = tanhf(acc0.w);
        t1.x = tanhf(acc1.x); t1.y = tanhf(acc1.y); t1.z = tanhf(acc1.z); t1.w = tanhf(acc1.w);
        *reinterpret_cast<float4*>(&Ht[r0 * LDH + cq * 4]) = t0;
        *reinterpret_cast<float4*>(&Ht[r1 * LDH + cq * 4]) = t1;
    }
    __syncthreads();

    // ---- fc1: 32x32, tile 2x4, 128 threads ----
    if (tid < 128) {
        const int rp = tid >> 3;          // 0..15
        const int cq = tid & 7;           // cols 4cq..4cq+3
        const int r0 = rp * 2, r1 = r0 + 1;
        const float4 bias = reinterpret_cast<const float4*>(fb1)[cq];
        float4 acc0 = bias, acc1 = bias;
        for (int k4 = 0; k4 < 64; k4 += 4) {
            const float4 a0 = *reinterpret_cast<const float4*>(&Ht[r0 * LDH + k4]);
            const float4 a1 = *reinterpret_cast<const float4*>(&Ht[r1 * LDH + k4]);
            const float4 w0 = *reinterpret_cast<const float4*>(&W1[(k4 + 0) * 32 + cq * 4]);
            const float4 w1 = *reinterpret_cast<const float4*>(&W1[(k4 + 1) * 32 + cq * 4]);
            const float4 w2 = *reinterpret_cast<const float4*>(&W1[(k4 + 2) * 32 + cq * 4]);
            const float4 w3 = *reinterpret_cast<const float4*>(&W1[(k4 + 3) * 32 + cq * 4]);
            acc0.x = fmaf(a0.x, w0.x, fmaf(a0.y, w1.x, fmaf(a0.z, w2.x, fmaf(a0.w, w3.x, acc0.x))));
            acc0.y = fmaf(a0.x, w0.y, fmaf(a0.y, w1.y, fmaf(a0.z, w2.y, fmaf(a0.w, w3.y, acc0.y))));
            acc0.z = fmaf(a0.x, w0.z, fmaf(a0.y, w1.z, fmaf(a0.z, w2.z, fmaf(a0.w, w3.z, acc0.z))));
            acc0.w = fmaf(a0.x, w0.w, fmaf(a0.y, w1.w, fmaf(a0.z, w2.w, fmaf(a0.w, w3.w, acc0.w))));
            acc1.x = fmaf(a1.x, w0.x, fmaf(a1.y, w1.x, fmaf(a1.z, w2.x, fmaf(a1.w, w3.x, acc1.x))));
            acc1.y = fmaf(a1.x, w0.y, fmaf(a1.y, w1.y, fmaf(a1.z, w2.y, fmaf(a1.w, w3.y, acc1.y))));
            acc1.z = fmaf(a1.x, w0.z, fmaf(a1.y, w1.z, fmaf(a1.z, w2.z, fmaf(a1.w, w3.z, acc1.z))));
            acc1.w = fmaf(a1.x, w0.w, fmaf(a1.y, w1.w, fmaf(a1.z, w2.w, fmaf(a1.w, w3.w, acc1.w))));
        }
        // scalar stores (Hs row stride 33 is not 16B-aligned)
        Hs[r0 * 33 + cq * 4 + 0] = tanhf(acc0.x);
        Hs[r0 * 33 + cq * 4 + 1] = tanhf(acc0.y);
        Hs[r0 * 33 + cq * 4 + 2] = tanhf(acc0.z);
        Hs[r0 * 33 + cq * 4 + 3] = tanhf(acc0.w);
        Hs[r1 * 33 + cq * 4 + 0] = tanhf(acc1.x);
        Hs[r1 * 33 + cq * 4 + 1] = tanhf(acc1.y);
        Hs[r1 * 33 + cq * 4 + 2] = tanhf(acc1.z);
        Hs[r1 * 33 + cq * 4 + 3] = tanhf(acc1.w);
    }
    __syncthreads();

    // ---- fc2: 32 -> 1 ----
    if (tid < BR) {
        float a = W2s[32];
        for (int k = 0; k < 32; ++k) a = fmaf(Hs[tid * 33 + k], W2s[k], a);
        out[row0 + tid] = a;
    }
}

// ---------------- launch ----------------

extern "C" void kernel_launch(void* const* d_in, const int* in_sizes, int n_in,
                              void* d_out, int out_size, void* d_ws, size_t ws_size,
                              hipStream_t stream) {
    const float* x    = (const float*)d_in[0];
    const int*   eidx = (const int*)d_in[1];
    const float* cW0  = (const float*)d_in[2];
    const float* cb0  = (const float*)d_in[3];
    const float* cW1  = (const float*)d_in[4];
    const float* cb1  = (const float*)d_in[5];
    const float* fW0  = (const float*)d_in[6];
    const float* fb0  = (const float*)d_in[7];
    const float* fW1  = (const float*)d_in[8];
    const float* fb1  = (const float*)d_in[9];
    const float* fW2  = (const float*)d_in[10];
    const float* fb2  = (const float*)d_in[11];
    float* out = (float*)d_out;

    const int* src = eidx;
    const int* dst = eidx + N_EDGES;

    char* ws = (char*)d_ws;
    unsigned* hist   = (unsigned*)(ws);                  // 400,000
    unsigned* rowptr = (unsigned*)(ws + 400000);         // 400,004
    float*    dinv   = (float*)   (ws + 800016);         // 400,000
    unsigned* bs     = (unsigned*)(ws + 1200016);        // 1,564
    unsigned* gbcur  = (unsigned*)(ws + 1201584);        // 1,564
    int*      ssrc   = (int*)     (ws + 1203200);        // 6,400,000
    ushort_t* xlb    = (ushort_t*)(ws + 7603200);        // 12,800,000
    unsigned* binned = (unsigned*)(ws + 20403200);       // 6,400,000
    float*    bufB   = (float*)   (ws + 26803200);       // 25,600,000 -> ends 52,403,200

    const int gE   = (N_EDGES + 255) / 256;   // 6250
    const int gRow = N_NODES / 32;            // 3125
    const int gAgg = N_NODES / 4;             // 25000

    // rowptr + dinv
    k_zero_u32<<<NBLK_N, 256, 0, stream>>>(hist, N_NODES);
    k_hist<<<gE, 256, 0, stream>>>(dst, hist);
    k_blocksum<<<NBLK_N, 256, 0, stream>>>(hist, bs);
    k_scanbs<<<1, 512, 0, stream>>>(bs);
    k_scan_final<<<NBLK_N, 256, 0, stream>>>(hist, bs, rowptr, dinv);
    // CSR fill via two-phase multisplit
    k_init_bcur<<<2, 256, 0, stream>>>(rowptr, gbcur);
    k_bin<<<NBLK_A, 256, 0, stream>>>(src, dst, gbcur, binned);
    k_csr_fill<<<NB, 256, 0, stream>>>(binned, rowptr, ssrc);

    // conv0
    k_gemm_bf<128, 64><<<gRow, 256, 0, stream>>>(x, cW0, dinv, xlb);
    k_agg<<<gAgg, 256, 0, stream>>>(xlb, dinv, rowptr, ssrc, cb0, bufB);
    // conv1
    k_gemm_bf<64, 64><<<gRow, 256, 0, stream>>>(bufB, cW1, dinv, xlb);
    k_agg<<<gAgg, 256, 0, stream>>>(xlb, dinv, rowptr, ssrc, cb1, bufB);
    // fc stack
    k_fc<<<gRow, 256, 0, stream>>>(bufB, fW0, fb0, fW1, fb1, fW2, fb2, out);
}

// Round 6
// 332.470 us; speedup vs baseline: 1.2558x; 1.2558x over previous
//
#include <hip/hip_runtime.h>
#include <math.h>

#define N_NODES 100000
#define N_EDGES 1600000
#define NBLK_N 391   // ceil(N/256)
#define NB     391   // buckets of 256 nodes
#define CHUNK  4096  // edges per k_bin block
#define NBLK_A 391   // ceil(E/CHUNK)

typedef unsigned short ushort_t;

__device__ inline unsigned short f2bf(float f) {
    unsigned u = __float_as_uint(f);
    unsigned r = (u + 0x7FFFu + ((u >> 16) & 1u)) >> 16;
    return (unsigned short)r;
}
// accumulate 2 packed bf16 (little-endian: lo=bits[15:0]) into 2 fp32
__device__ inline void acc2(float& a0, float& a1, unsigned u) {
    a0 += __uint_as_float(u << 16);
    a1 += __uint_as_float(u & 0xFFFF0000u);
}

// ---------------- degree + rowptr ----------------

__global__ __launch_bounds__(256) void k_zero_u32(unsigned* __restrict__ p, int n) {
    int i = blockIdx.x * 256 + threadIdx.x;
    if (i < n) p[i] = 0u;
}

__global__ __launch_bounds__(256) void k_hist(const int* __restrict__ dst,
                                              unsigned* __restrict__ hist) {
    int e = blockIdx.x * 256 + threadIdx.x;
    if (e < N_EDGES) atomicAdd(&hist[dst[e]], 1u);
}

__global__ __launch_bounds__(256) void k_blocksum(const unsigned* __restrict__ hist,
                                                  unsigned* __restrict__ bs) {
    __shared__ unsigned s[256];
    int i = blockIdx.x * 256 + threadIdx.x;
    unsigned v = (i < N_NODES) ? hist[i] : 0u;
    s[threadIdx.x] = v;
    __syncthreads();
    for (int o = 128; o > 0; o >>= 1) {
        if (threadIdx.x < o) s[threadIdx.x] += s[threadIdx.x + o];
        __syncthreads();
    }
    if (threadIdx.x == 0) bs[blockIdx.x] = s[0];
}

__global__ __launch_bounds__(512) void k_scanbs(unsigned* __restrict__ bs) {
    __shared__ unsigned s[512];
    int tid = threadIdx.x;
    unsigned v = (tid < NBLK_N) ? bs[tid] : 0u;
    s[tid] = v;
    __syncthreads();
    for (int o = 1; o < 512; o <<= 1) {
        unsigned t = (tid >= o) ? s[tid - o] : 0u;
        __syncthreads();
        s[tid] += t;
        __syncthreads();
    }
    if (tid < NBLK_N) bs[tid] = s[tid] - v;   // exclusive
}

__global__ __launch_bounds__(256) void k_scan_final(const unsigned* __restrict__ hist,
                                                    const unsigned* __restrict__ bs,
                                                    unsigned* __restrict__ rowptr,
                                                    float* __restrict__ dinv) {
    __shared__ unsigned s[256];
    int tid = threadIdx.x;
    int i = blockIdx.x * 256 + tid;
    unsigned v = (i < N_NODES) ? hist[i] : 0u;
    s[tid] = v;
    __syncthreads();
    for (int o = 1; o < 256; o <<= 1) {
        unsigned t = (tid >= o) ? s[tid - o] : 0u;
        __syncthreads();
        s[tid] += t;
        __syncthreads();
    }
    unsigned excl = s[tid] - v + bs[blockIdx.x];
    if (i < N_NODES) {
        rowptr[i] = excl;
        dinv[i] = rsqrtf((float)(v + 1u));
        if (i == N_NODES - 1) rowptr[N_NODES] = excl + v;  // == E
    }
}

__global__ __launch_bounds__(256) void k_init_bcur(const unsigned* __restrict__ rowptr,
                                                   unsigned* __restrict__ gbcur) {
    int t = blockIdx.x * 256 + threadIdx.x;
    if (t < NB) gbcur[t] = rowptr[t * 256];
}

// ---------------- phase A: LDS multisplit into 391 buckets ----------------
__global__ __launch_bounds__(256) void k_bin(const int* __restrict__ src,
                                             const int* __restrict__ dst,
                                             unsigned* __restrict__ gbcur,
                                             unsigned* __restrict__ binned) {
    __shared__ unsigned cntA[NB];
    __shared__ unsigned excl[NB];
    __shared__ unsigned gbase[NB];
    __shared__ unsigned scanbuf[512];
    __shared__ unsigned data[CHUNK];
    const int tid = threadIdx.x;
    const long e0 = (long)blockIdx.x * CHUNK;

    for (int i = tid; i < NB; i += 256) cntA[i] = 0u;
    __syncthreads();
    for (int i = tid; i < CHUNK; i += 256) {
        long e = e0 + i;
        if (e < N_EDGES) atomicAdd(&cntA[((unsigned)dst[e]) >> 8], 1u);
    }
    __syncthreads();
    scanbuf[tid] = (tid < NB) ? cntA[tid] : 0u;
    scanbuf[tid + 256] = (tid + 256 < NB) ? cntA[tid + 256] : 0u;
    __syncthreads();
    for (int o = 1; o < 512; o <<= 1) {
        unsigned v0 = (tid >= o) ? scanbuf[tid - o] : 0u;
        unsigned v1 = (tid + 256 >= o) ? scanbuf[tid + 256 - o] : 0u;
        __syncthreads();
        scanbuf[tid] += v0;
        scanbuf[tid + 256] += v1;
        __syncthreads();
    }
    for (int b = tid; b < NB; b += 256) {
        unsigned c = cntA[b];
        excl[b] = scanbuf[b] - c;
        gbase[b] = c ? atomicAdd(&gbcur[b], c) : 0u;
    }
    __syncthreads();
    for (int i = tid; i < NB; i += 256) cntA[i] = 0u;
    __syncthreads();
    for (int i = tid; i < CHUNK; i += 256) {
        long e = e0 + i;
        if (e < N_EDGES) {
            unsigned d = (unsigned)dst[e];
            unsigned b = d >> 8;
            unsigned slot = excl[b] + atomicAdd(&cntA[b], 1u);
            data[slot] = (((unsigned)src[e]) << 8) | (d & 255u);
        }
    }
    __syncthreads();
    const int w = tid >> 6, lane = tid & 63;
    for (int b = w; b < NB; b += 4) {
        unsigned c = cntA[b];
        unsigned sb = excl[b], gb = gbase[b];
        for (unsigned k = lane; k < c; k += 64)
            binned[gb + k] = data[sb + k];
    }
}

// ---------------- phase B: per-bucket CSR fill (LDS cursors) ----------------
__global__ __launch_bounds__(256) void k_csr_fill(const unsigned* __restrict__ binned,
                                                  const unsigned* __restrict__ rowptr,
                                                  int* __restrict__ ssrc) {
    __shared__ unsigned cur[256];
    const int b = blockIdx.x;
    const int tid = threadIdx.x;
    const int n0 = b * 256;
    const int n1 = (n0 + 256 < N_NODES) ? n0 + 256 : N_NODES;
    if (tid < n1 - n0) cur[tid] = rowptr[n0 + tid];
    __syncthreads();
    const unsigned beg = rowptr[n0], end = rowptr[n1];
    for (unsigned i = beg + tid; i < end; i += 256) {
        unsigned p = binned[i];
        unsigned pos = atomicAdd(&cur[p & 255u], 1u);
        ssrc[pos] = (int)(p >> 8);
    }
}

// ---------------- dense layers ----------------

// xlb[N x OUT] (bf16) = (A[N x K] @ W[K x OUT]) * dinv[row]
template<int K, int OUT>
__global__ __launch_bounds__(256) void k_gemm_bf(const float* __restrict__ A,
                                                 const float* __restrict__ W,
                                                 const float* __restrict__ dinv,
                                                 ushort_t* __restrict__ C) {
    constexpr int BR = 32;
    __shared__ float Wld[K * OUT];
    __shared__ float Ald[BR * K];
    const int tid = threadIdx.x;
    for (int i = tid; i < K * OUT; i += 256) Wld[i] = W[i];
    const long row0 = (long)blockIdx.x * BR;
    const float4* A4 = reinterpret_cast<const float4*>(A + row0 * K);
    float4* Ald4w = reinterpret_cast<float4*>(Ald);
    constexpr int NV = BR * K / 4;
    for (int i = tid; i < NV; i += 256) Ald4w[i] = A4[i];
    __syncthreads();

    constexpr int RG = 256 / OUT;
    constexpr int RPT = BR / RG;
    const int col = tid % OUT;
    const int rg = tid / OUT;
    const float4* Ald4 = reinterpret_cast<const float4*>(Ald);
    float acc[RPT];
#pragma unroll
    for (int j = 0; j < RPT; ++j) acc[j] = 0.f;
    for (int k4 = 0; k4 < K; k4 += 4) {
        const float w0 = Wld[(k4 + 0) * OUT + col];
        const float w1 = Wld[(k4 + 1) * OUT + col];
        const float w2 = Wld[(k4 + 2) * OUT + col];
        const float w3 = Wld[(k4 + 3) * OUT + col];
#pragma unroll
        for (int j = 0; j < RPT; ++j) {
            const float4 a = Ald4[((rg + j * RG) * K + k4) >> 2];
            acc[j] = fmaf(a.x, w0, fmaf(a.y, w1, fmaf(a.z, w2, fmaf(a.w, w3, acc[j]))));
        }
    }
#pragma unroll
    for (int j = 0; j < RPT; ++j) {
        const long r = row0 + rg + j * RG;
        C[r * OUT + col] = f2bf(acc[j] * dinv[r]);
    }
}

// one node per 64-lane wave; 8 lane-groups x 8 lanes; lane loads uint4 = 8 bf16.
// 16 edge-gathers in flight per wave (8 groups x unroll 2).
__global__ __launch_bounds__(256) void k_agg(const ushort_t* __restrict__ xlb,
                                             const float* __restrict__ dinv,
                                             const unsigned* __restrict__ rowptr,
                                             const int* __restrict__ ssrc,
                                             const float* __restrict__ bias,
                                             float* __restrict__ h) {
    const int node = blockIdx.x * 4 + (threadIdx.x >> 6);
    const int lane = threadIdx.x & 63;
    const int g = lane >> 3;        // edge group 0..7
    const int l = lane & 7;         // feature octet 0..7 (features l*8..l*8+7)
    const uint4* xb4 = reinterpret_cast<const uint4*>(xlb);  // 8 uint4 per row

    const unsigned beg = rowptr[node], end = rowptr[node + 1];
    float a[8] = {0.f,0.f,0.f,0.f,0.f,0.f,0.f,0.f};
    float b[8] = {0.f,0.f,0.f,0.f,0.f,0.f,0.f,0.f};
    if (g == 0) {   // self-loop
        const uint4 v = xb4[(size_t)node * 8 + l];
        acc2(a[0], a[1], v.x); acc2(a[2], a[3], v.y);
        acc2(a[4], a[5], v.z); acc2(a[6], a[7], v.w);
    }
    unsigned j = beg + g;
    for (; j + 8 < end; j += 16) {
        const int s0 = ssrc[j];
        const int s1 = ssrc[j + 8];
        const uint4 v0 = xb4[(size_t)s0 * 8 + l];
        const uint4 v1 = xb4[(size_t)s1 * 8 + l];
        acc2(a[0], a[1], v0.x); acc2(a[2], a[3], v0.y);
        acc2(a[4], a[5], v0.z); acc2(a[6], a[7], v0.w);
        acc2(b[0], b[1], v1.x); acc2(b[2], b[3], v1.y);
        acc2(b[4], b[5], v1.z); acc2(b[6], b[7], v1.w);
    }
    if (j < end) {
        const uint4 v = xb4[(size_t)ssrc[j] * 8 + l];
        acc2(a[0], a[1], v.x); acc2(a[2], a[3], v.y);
        acc2(a[4], a[5], v.z); acc2(a[6], a[7], v.w);
    }
#pragma unroll
    for (int i = 0; i < 8; ++i) a[i] += b[i];
#pragma unroll
    for (int i = 0; i < 8; ++i) {
        a[i] += __shfl_xor(a[i], 8);
        a[i] += __shfl_xor(a[i], 16);
        a[i] += __shfl_xor(a[i], 32);
    }
    if (g == 0) {
        const float di = dinv[node];
        const float4 b0 = reinterpret_cast<const float4*>(bias)[l * 2];
        const float4 b1 = reinterpret_cast<const float4*>(bias)[l * 2 + 1];
        float4 r0, r1;
        r0.x = tanhf(fmaf(a[0], di, b0.x));
        r0.y = tanhf(fmaf(a[1], di, b0.y));
        r0.z = tanhf(fmaf(a[2], di, b0.z));
        r0.w = tanhf(fmaf(a[3], di, b0.w));
        r1.x = tanhf(fmaf(a[4], di, b1.x));
        r1.y = tanhf(fmaf(a[5], di, b1.y));
        r1.z = tanhf(fmaf(a[6], di, b1.z));
        r1.w = tanhf(fmaf(a[7], di, b1.w));
        float4* hp = reinterpret_cast<float4*>(h) + (size_t)node * 16 + l * 2;
        hp[0] = r0;
        hp[1] = r1;
    }
}

// fused FC stack, register-tiled fp32 with CONTROLLED unrolling.
// __launch_bounds__(256,4) caps VGPR at 128; #pragma unroll 2 keeps ~12 loads live.
// Hin/Ht padded to 68 floats/row -> per-lane row addresses land on distinct banks.
__global__ __launch_bounds__(256, 4) void k_fc(const float* __restrict__ h2,
                                               const float* __restrict__ fW0, const float* __restrict__ fb0,
                                               const float* __restrict__ fW1, const float* __restrict__ fb1,
                                               const float* __restrict__ fW2, const float* __restrict__ fb2,
                                               float* __restrict__ out) {
    constexpr int BR = 32;
    constexpr int LDH = 68;
    __shared__ float W0[64 * 64];
    __shared__ float W1[64 * 32];
    __shared__ float Hin[BR * LDH];
    __shared__ float Ht[BR * LDH];
    __shared__ float Hs[BR * 33];
    __shared__ float W2s[33];
    const int tid = threadIdx.x;
    {
        const float4* w04 = reinterpret_cast<const float4*>(fW0);
        float4* W04 = reinterpret_cast<float4*>(W0);
        for (int i = tid; i < 64 * 16; i += 256) W04[i] = w04[i];
        const float4* w14 = reinterpret_cast<const float4*>(fW1);
        float4* W14 = reinterpret_cast<float4*>(W1);
        for (int i = tid; i < 64 * 8; i += 256) W14[i] = w14[i];
        if (tid < 32) W2s[tid] = fW2[tid];
        if (tid == 32) W2s[32] = fb2[0];
    }
    const long row0 = (long)blockIdx.x * BR;
    {
        const float4* H4 = reinterpret_cast<const float4*>(h2 + row0 * 64);
        for (int i = tid; i < BR * 16; i += 256) {
            int r = i >> 4, q = i & 15;
            *reinterpret_cast<float4*>(&Hin[r * LDH + q * 4]) = H4[i];
        }
    }
    __syncthreads();

    // ---- fc0: 32x64, tile 2 rows x 4 cols, 256 threads ----
    {
        const int rp = tid >> 4;          // 0..15 -> rows 2rp, 2rp+1
        const int cq = tid & 15;          // cols 4cq..4cq+3
        const int r0 = rp * 2, r1 = r0 + 1;
        const float4 bias = reinterpret_cast<const float4*>(fb0)[cq];
        float4 acc0 = bias, acc1 = bias;
#pragma unroll 2
        for (int k4 = 0; k4 < 64; k4 += 4) {
            const float4 a0 = *reinterpret_cast<const float4*>(&Hin[r0 * LDH + k4]);
            const float4 a1 = *reinterpret_cast<const float4*>(&Hin[r1 * LDH + k4]);
            const float4 w0 = *reinterpret_cast<const float4*>(&W0[(k4 + 0) * 64 + cq * 4]);
            const float4 w1 = *reinterpret_cast<const float4*>(&W0[(k4 + 1) * 64 + cq * 4]);
            const float4 w2 = *reinterpret_cast<const float4*>(&W0[(k4 + 2) * 64 + cq * 4]);
            const float4 w3 = *reinterpret_cast<const float4*>(&W0[(k4 + 3) * 64 + cq * 4]);
            acc0.x = fmaf(a0.x, w0.x, fmaf(a0.y, w1.x, fmaf(a0.z, w2.x, fmaf(a0.w, w3.x, acc0.x))));
            acc0.y = fmaf(a0.x, w0.y, fmaf(a0.y, w1.y, fmaf(a0.z, w2.y, fmaf(a0.w, w3.y, acc0.y))));
            acc0.z = fmaf(a0.x, w0.z, fmaf(a0.y, w1.z, fmaf(a0.z, w2.z, fmaf(a0.w, w3.z, acc0.z))));
            acc0.w = fmaf(a0.x, w0.w, fmaf(a0.y, w1.w, fmaf(a0.z, w2.w, fmaf(a0.w, w3.w, acc0.w))));
            acc1.x = fmaf(a1.x, w0.x, fmaf(a1.y, w1.x, fmaf(a1.z, w2.x, fmaf(a1.w, w3.x, acc1.x))));
            acc1.y = fmaf(a1.x, w0.y, fmaf(a1.y, w1.y, fmaf(a1.z, w2.y, fmaf(a1.w, w3.y, acc1.y))));
            acc1.z = fmaf(a1.x, w0.z, fmaf(a1.y, w1.z, fmaf(a1.z, w2.z, fmaf(a1.w, w3.z, acc1.z))));
            acc1.w = fmaf(a1.x, w0.w, fmaf(a1.y, w1.w, fmaf(a1.z, w2.w, fmaf(a1.w, w3.w, acc1.w))));
        }
        float4 t0, t1;
        t0.x = tanhf(acc0.x); t0.y = tanhf(acc0.y); t0.z = tanhf(acc0.z); t0.w = tanhf(acc0.w);
        t1.x = tanhf(acc1.x); t1.y = tanhf(acc1.y); t1.z = tanhf(acc1.z); t1.w = tanhf(acc1.w);
        *reinterpret_cast<float4*>(&Ht[r0 * LDH + cq * 4]) = t0;
        *reinterpret_cast<float4*>(&Ht[r1 * LDH + cq * 4]) = t1;
    }
    __syncthreads();

    // ---- fc1: 32x32, tile 1 row x 4 cols, 256 threads ----
    {
        const int r = tid >> 3;           // 0..31
        const int cq = tid & 7;           // cols 4cq..4cq+3
        const float4 bias = reinterpret_cast<const float4*>(fb1)[cq];
        float4 acc0 = bias;
#pragma unroll 2
        for (int k4 = 0; k4 < 64; k4 += 4) {
            const float4 a0 = *reinterpret_cast<const float4*>(&Ht[r * LDH + k4]);
            const float4 w0 = *reinterpret_cast<const float4*>(&W1[(k4 + 0) * 32 + cq * 4]);
            const float4 w1 = *reinterpret_cast<const float4*>(&W1[(k4 + 1) * 32 + cq * 4]);
            const float4 w2 = *reinterpret_cast<const float4*>(&W1[(k4 + 2) * 32 + cq * 4]);
            const float4 w3 = *reinterpret_cast<const float4*>(&W1[(k4 + 3) * 32 + cq * 4]);
            acc0.x = fmaf(a0.x, w0.x, fmaf(a0.y, w1.x, fmaf(a0.z, w2.x, fmaf(a0.w, w3.x, acc0.x))));
            acc0.y = fmaf(a0.x, w0.y, fmaf(a0.y, w1.y, fmaf(a0.z, w2.y, fmaf(a0.w, w3.y, acc0.y))));
            acc0.z = fmaf(a0.x, w0.z, fmaf(a0.y, w1.z, fmaf(a0.z, w2.z, fmaf(a0.w, w3.z, acc0.z))));
            acc0.w = fmaf(a0.x, w0.w, fmaf(a0.y, w1.w, fmaf(a0.z, w2.w, fmaf(a0.w, w3.w, acc0.w))));
        }
        Hs[r * 33 + cq * 4 + 0] = tanhf(acc0.x);
        Hs[r * 33 + cq * 4 + 1] = tanhf(acc0.y);
        Hs[r * 33 + cq * 4 + 2] = tanhf(acc0.z);
        Hs[r * 33 + cq * 4 + 3] = tanhf(acc0.w);
    }
    __syncthreads();

    // ---- fc2: 32 -> 1 ----
    if (tid < BR) {
        float a = W2s[32];
        for (int k = 0; k < 32; ++k) a = fmaf(Hs[tid * 33 + k], W2s[k], a);
        out[row0 + tid] = a;
    }
}

// ---------------- launch ----------------

extern "C" void kernel_launch(void* const* d_in, const int* in_sizes, int n_in,
                              void* d_out, int out_size, void* d_ws, size_t ws_size,
                              hipStream_t stream) {
    const float* x    = (const float*)d_in[0];
    const int*   eidx = (const int*)d_in[1];
    const float* cW0  = (const float*)d_in[2];
    const float* cb0  = (const float*)d_in[3];
    const float* cW1  = (const float*)d_in[4];
    const float* cb1  = (const float*)d_in[5];
    const float* fW0  = (const float*)d_in[6];
    const float* fb0  = (const float*)d_in[7];
    const float* fW1  = (const float*)d_in[8];
    const float* fb1  = (const float*)d_in[9];
    const float* fW2  = (const float*)d_in[10];
    const float* fb2  = (const float*)d_in[11];
    float* out = (float*)d_out;

    const int* src = eidx;
    const int* dst = eidx + N_EDGES;

    char* ws = (char*)d_ws;
    unsigned* hist   = (unsigned*)(ws);                  // 400,000
    unsigned* rowptr = (unsigned*)(ws + 400000);         // 400,004
    float*    dinv   = (float*)   (ws + 800016);         // 400,000
    unsigned* bs     = (unsigned*)(ws + 1200016);        // 1,564
    unsigned* gbcur  = (unsigned*)(ws + 1201584);        // 1,564
    int*      ssrc   = (int*)     (ws + 1203200);        // 6,400,000
    ushort_t* xlb    = (ushort_t*)(ws + 7603200);        // 12,800,000
    unsigned* binned = (unsigned*)(ws + 20403200);       // 6,400,000
    float*    bufB   = (float*)   (ws + 26803200);       // 25,600,000 -> ends 52,403,200

    const int gE   = (N_EDGES + 255) / 256;   // 6250
    const int gRow = N_NODES / 32;            // 3125
    const int gAgg = N_NODES / 4;             // 25000

    // rowptr + dinv
    k_zero_u32<<<NBLK_N, 256, 0, stream>>>(hist, N_NODES);
    k_hist<<<gE, 256, 0, stream>>>(dst, hist);
    k_blocksum<<<NBLK_N, 256, 0, stream>>>(hist, bs);
    k_scanbs<<<1, 512, 0, stream>>>(bs);
    k_scan_final<<<NBLK_N, 256, 0, stream>>>(hist, bs, rowptr, dinv);
    // CSR fill via two-phase multisplit
    k_init_bcur<<<2, 256, 0, stream>>>(rowptr, gbcur);
    k_bin<<<NBLK_A, 256, 0, stream>>>(src, dst, gbcur, binned);
    k_csr_fill<<<NB, 256, 0, stream>>>(binned, rowptr, ssrc);

    // conv0
    k_gemm_bf<128, 64><<<gRow, 256, 0, stream>>>(x, cW0, dinv, xlb);
    k_agg<<<gAgg, 256, 0, stream>>>(xlb, dinv, rowptr, ssrc, cb0, bufB);
    // conv1
    k_gemm_bf<64, 64><<<gRow, 256, 0, stream>>>(bufB, cW1, dinv, xlb);
    k_agg<<<gAgg, 256, 0, stream>>>(xlb, dinv, rowptr, ssrc, cb1, bufB);
    // fc stack
    k_fc<<<gRow, 256, 0, stream>>>(bufB, fW0, fb0, fW1, fb1, fW2, fb2, out);
}

// Round 7
// 274.461 us; speedup vs baseline: 1.5213x; 1.2114x over previous
//
#include <hip/hip_runtime.h>
#include <math.h>

#define N_NODES 100000
#define N_EDGES 1600000
#define NB     391   // buckets of 256 nodes
#define CHUNK  4096  // edges per chunk block
#define NBLK_A 391   // ceil(E/CHUNK)

typedef unsigned short ushort_t;

__device__ inline unsigned short f2bf(float f) {
    unsigned u = __float_as_uint(f);
    unsigned r = (u + 0x7FFFu + ((u >> 16) & 1u)) >> 16;
    return (unsigned short)r;
}
// accumulate 2 packed bf16 (little-endian: lo=bits[15:0]) into 2 fp32
__device__ inline void acc2(float& a0, float& a1, unsigned u) {
    a0 += __uint_as_float(u << 16);
    a1 += __uint_as_float(u & 0xFFFF0000u);
}

// ---------------- CSR build: deterministic 3-level multisplit ----------------

// per-chunk LDS histogram of coarse buckets -> cnt[b * NBLK_A + blk] (no atomics)
__global__ __launch_bounds__(256) void k_count(const int* __restrict__ dst,
                                               unsigned* __restrict__ cnt) {
    __shared__ unsigned h[NB];
    const int tid = threadIdx.x;
    const long e0 = (long)blockIdx.x * CHUNK;
    for (int i = tid; i < NB; i += 256) h[i] = 0u;
    __syncthreads();
    for (int i = tid; i < CHUNK; i += 256) {
        long e = e0 + i;
        if (e < N_EDGES) atomicAdd(&h[((unsigned)dst[e]) >> 8], 1u);
    }
    __syncthreads();
    for (int b = tid; b < NB; b += 256) cnt[b * NBLK_A + blockIdx.x] = h[b];
}

// block b: exclusive scan of cnt[b][*] over blocks; emit bucket total
__global__ __launch_bounds__(512) void k_bucket_scan(unsigned* __restrict__ cnt,
                                                     unsigned* __restrict__ btot) {
    __shared__ unsigned s[512];
    const int tid = threadIdx.x;
    const int b = blockIdx.x;
    unsigned v = (tid < NBLK_A) ? cnt[b * NBLK_A + tid] : 0u;
    s[tid] = v;
    __syncthreads();
    for (int o = 1; o < 512; o <<= 1) {
        unsigned t = (tid >= o) ? s[tid - o] : 0u;
        __syncthreads();
        s[tid] += t;
        __syncthreads();
    }
    if (tid < NBLK_A) cnt[b * NBLK_A + tid] = s[tid] - v;   // exclusive within bucket
    if (tid == NBLK_A - 1) btot[b] = s[tid];
}

// 1 block: exclusive scan of btot[NB] -> bktbase[NB+1] (sentinel = E)
__global__ __launch_bounds__(512) void k_scan_bkt(const unsigned* __restrict__ btot,
                                                  unsigned* __restrict__ bktbase) {
    __shared__ unsigned s[512];
    const int tid = threadIdx.x;
    unsigned v = (tid < NB) ? btot[tid] : 0u;
    s[tid] = v;
    __syncthreads();
    for (int o = 1; o < 512; o <<= 1) {
        unsigned t = (tid >= o) ? s[tid - o] : 0u;
        __syncthreads();
        s[tid] += t;
        __syncthreads();
    }
    if (tid < NB) bktbase[tid] = s[tid] - v;
    if (tid == NB - 1) bktbase[NB] = s[tid];   // == E
}

// phase A: LDS multisplit into 391 buckets; base from scanned cnt matrix (no atomics)
// binned[pos] = (src<<8) | (dst&255), grouped by bucket = dst>>8
__global__ __launch_bounds__(256) void k_bin(const int* __restrict__ src,
                                             const int* __restrict__ dst,
                                             const unsigned* __restrict__ cnt,
                                             const unsigned* __restrict__ bktbase,
                                             unsigned* __restrict__ binned) {
    __shared__ unsigned cntA[NB];
    __shared__ unsigned excl[NB];
    __shared__ unsigned gbase[NB];
    __shared__ unsigned scanbuf[512];
    __shared__ unsigned data[CHUNK];
    const int tid = threadIdx.x;
    const long e0 = (long)blockIdx.x * CHUNK;

    for (int i = tid; i < NB; i += 256) cntA[i] = 0u;
    __syncthreads();
    for (int i = tid; i < CHUNK; i += 256) {
        long e = e0 + i;
        if (e < N_EDGES) atomicAdd(&cntA[((unsigned)dst[e]) >> 8], 1u);
    }
    __syncthreads();
    scanbuf[tid] = (tid < NB) ? cntA[tid] : 0u;
    scanbuf[tid + 256] = (tid + 256 < NB) ? cntA[tid + 256] : 0u;
    __syncthreads();
    for (int o = 1; o < 512; o <<= 1) {
        unsigned v0 = (tid >= o) ? scanbuf[tid - o] : 0u;
        unsigned v1 = (tid + 256 >= o) ? scanbuf[tid + 256 - o] : 0u;
        __syncthreads();
        scanbuf[tid] += v0;
        scanbuf[tid + 256] += v1;
        __syncthreads();
    }
    for (int b = tid; b < NB; b += 256) {
        excl[b] = scanbuf[b] - cntA[b];
        gbase[b] = bktbase[b] + cnt[b * NBLK_A + blockIdx.x];
    }
    __syncthreads();
    for (int i = tid; i < NB; i += 256) cntA[i] = 0u;
    __syncthreads();
    for (int i = tid; i < CHUNK; i += 256) {
        long e = e0 + i;
        if (e < N_EDGES) {
            unsigned d = (unsigned)dst[e];
            unsigned b = d >> 8;
            unsigned slot = excl[b] + atomicAdd(&cntA[b], 1u);
            data[slot] = (((unsigned)src[e]) << 8) | (d & 255u);
        }
    }
    __syncthreads();
    const int w = tid >> 6, lane = tid & 63;
    for (int b = w; b < NB; b += 4) {
        unsigned c = cntA[b];
        unsigned sb = excl[b], gb = gbase[b];
        for (unsigned k = lane; k < c; k += 64)
            binned[gb + k] = data[sb + k];
    }
}

// phase B: per-bucket CSR fill; derives degree/rowptr/dinv from binned (LDS only)
__global__ __launch_bounds__(256) void k_csr_fill2(const unsigned* __restrict__ binned,
                                                   const unsigned* __restrict__ bktbase,
                                                   unsigned* __restrict__ rowptr,
                                                   float* __restrict__ dinv,
                                                   int* __restrict__ ssrc) {
    __shared__ unsigned cnt[256];
    __shared__ unsigned s[256];
    __shared__ unsigned cur[256];
    const int b = blockIdx.x;
    const int tid = threadIdx.x;
    const int n0 = b * 256;
    const unsigned beg = bktbase[b], end = bktbase[b + 1];
    cnt[tid] = 0u;
    __syncthreads();
    for (unsigned i = beg + tid; i < end; i += 256)
        atomicAdd(&cnt[binned[i] & 255u], 1u);
    __syncthreads();
    const unsigned v = cnt[tid];
    s[tid] = v;
    __syncthreads();
    for (int o = 1; o < 256; o <<= 1) {
        unsigned t = (tid >= o) ? s[tid - o] : 0u;
        __syncthreads();
        s[tid] += t;
        __syncthreads();
    }
    const unsigned excl = s[tid] - v;
    const int node = n0 + tid;
    if (node < N_NODES) {
        rowptr[node] = beg + excl;
        dinv[node] = rsqrtf((float)(v + 1u));
        if (node == N_NODES - 1) rowptr[N_NODES] = end;   // == E
    }
    cur[tid] = beg + excl;
    __syncthreads();
    for (unsigned i = beg + tid; i < end; i += 256) {
        unsigned p = binned[i];
        unsigned pos = atomicAdd(&cur[p & 255u], 1u);
        ssrc[pos] = (int)(p >> 8);
    }
}

// ---------------- dense layers ----------------

// xlb[N x OUT] (bf16) = (A[N x K] @ W[K x OUT]) * dinv[row]
template<int K, int OUT>
__global__ __launch_bounds__(256) void k_gemm_bf(const float* __restrict__ A,
                                                 const float* __restrict__ W,
                                                 const float* __restrict__ dinv,
                                                 ushort_t* __restrict__ C) {
    constexpr int BR = 32;
    __shared__ float Wld[K * OUT];
    __shared__ float Ald[BR * K];
    const int tid = threadIdx.x;
    for (int i = tid; i < K * OUT; i += 256) Wld[i] = W[i];
    const long row0 = (long)blockIdx.x * BR;
    const float4* A4 = reinterpret_cast<const float4*>(A + row0 * K);
    float4* Ald4w = reinterpret_cast<float4*>(Ald);
    constexpr int NV = BR * K / 4;
    for (int i = tid; i < NV; i += 256) Ald4w[i] = A4[i];
    __syncthreads();

    constexpr int RG = 256 / OUT;
    constexpr int RPT = BR / RG;
    const int col = tid % OUT;
    const int rg = tid / OUT;
    const float4* Ald4 = reinterpret_cast<const float4*>(Ald);
    float acc[RPT];
#pragma unroll
    for (int j = 0; j < RPT; ++j) acc[j] = 0.f;
    for (int k4 = 0; k4 < K; k4 += 4) {
        const float w0 = Wld[(k4 + 0) * OUT + col];
        const float w1 = Wld[(k4 + 1) * OUT + col];
        const float w2 = Wld[(k4 + 2) * OUT + col];
        const float w3 = Wld[(k4 + 3) * OUT + col];
#pragma unroll
        for (int j = 0; j < RPT; ++j) {
            const float4 a = Ald4[((rg + j * RG) * K + k4) >> 2];
            acc[j] = fmaf(a.x, w0, fmaf(a.y, w1, fmaf(a.z, w2, fmaf(a.w, w3, acc[j]))));
        }
    }
#pragma unroll
    for (int j = 0; j < RPT; ++j) {
        const long r = row0 + rg + j * RG;
        C[r * OUT + col] = f2bf(acc[j] * dinv[r]);
    }
}

// one node per 64-lane wave; 8 lane-groups x 8 lanes; lane loads uint4 = 8 bf16.
__global__ __launch_bounds__(256) void k_agg(const ushort_t* __restrict__ xlb,
                                             const float* __restrict__ dinv,
                                             const unsigned* __restrict__ rowptr,
                                             const int* __restrict__ ssrc,
                                             const float* __restrict__ bias,
                                             float* __restrict__ h) {
    const int node = blockIdx.x * 4 + (threadIdx.x >> 6);
    const int lane = threadIdx.x & 63;
    const int g = lane >> 3;        // edge group 0..7
    const int l = lane & 7;         // feature octet 0..7
    const uint4* xb4 = reinterpret_cast<const uint4*>(xlb);  // 8 uint4 per row

    const unsigned beg = rowptr[node], end = rowptr[node + 1];
    float a[8] = {0.f,0.f,0.f,0.f,0.f,0.f,0.f,0.f};
    float b[8] = {0.f,0.f,0.f,0.f,0.f,0.f,0.f,0.f};
    if (g == 0) {   // self-loop
        const uint4 v = xb4[(size_t)node * 8 + l];
        acc2(a[0], a[1], v.x); acc2(a[2], a[3], v.y);
        acc2(a[4], a[5], v.z); acc2(a[6], a[7], v.w);
    }
    unsigned j = beg + g;
    for (; j + 8 < end; j += 16) {
        const int s0 = ssrc[j];
        const int s1 = ssrc[j + 8];
        const uint4 v0 = xb4[(size_t)s0 * 8 + l];
        const uint4 v1 = xb4[(size_t)s1 * 8 + l];
        acc2(a[0], a[1], v0.x); acc2(a[2], a[3], v0.y);
        acc2(a[4], a[5], v0.z); acc2(a[6], a[7], v0.w);
        acc2(b[0], b[1], v1.x); acc2(b[2], b[3], v1.y);
        acc2(b[4], b[5], v1.z); acc2(b[6], b[7], v1.w);
    }
    if (j < end) {
        const uint4 v = xb4[(size_t)ssrc[j] * 8 + l];
        acc2(a[0], a[1], v.x); acc2(a[2], a[3], v.y);
        acc2(a[4], a[5], v.z); acc2(a[6], a[7], v.w);
    }
#pragma unroll
    for (int i = 0; i < 8; ++i) a[i] += b[i];
#pragma unroll
    for (int i = 0; i < 8; ++i) {
        a[i] += __shfl_xor(a[i], 8);
        a[i] += __shfl_xor(a[i], 16);
        a[i] += __shfl_xor(a[i], 32);
    }
    if (g == 0) {
        const float di = dinv[node];
        const float4 b0 = reinterpret_cast<const float4*>(bias)[l * 2];
        const float4 b1 = reinterpret_cast<const float4*>(bias)[l * 2 + 1];
        float4 r0, r1;
        r0.x = tanhf(fmaf(a[0], di, b0.x));
        r0.y = tanhf(fmaf(a[1], di, b0.y));
        r0.z = tanhf(fmaf(a[2], di, b0.z));
        r0.w = tanhf(fmaf(a[3], di, b0.w));
        r1.x = tanhf(fmaf(a[4], di, b1.x));
        r1.y = tanhf(fmaf(a[5], di, b1.y));
        r1.z = tanhf(fmaf(a[6], di, b1.z));
        r1.w = tanhf(fmaf(a[7], di, b1.w));
        float4* hp = reinterpret_cast<float4*>(h) + (size_t)node * 16 + l * 2;
        hp[0] = r0;
        hp[1] = r1;
    }
}

// fused FC stack, register-tiled fp32 with controlled unrolling.
__global__ __launch_bounds__(256, 4) void k_fc(const float* __restrict__ h2,
                                               const float* __restrict__ fW0, const float* __restrict__ fb0,
                                               const float* __restrict__ fW1, const float* __restrict__ fb1,
                                               const float* __restrict__ fW2, const float* __restrict__ fb2,
                                               float* __restrict__ out) {
    constexpr int BR = 32;
    constexpr int LDH = 68;
    __shared__ float W0[64 * 64];
    __shared__ float W1[64 * 32];
    __shared__ float Hin[BR * LDH];
    __shared__ float Ht[BR * LDH];
    __shared__ float Hs[BR * 33];
    __shared__ float W2s[33];
    const int tid = threadIdx.x;
    {
        const float4* w04 = reinterpret_cast<const float4*>(fW0);
        float4* W04 = reinterpret_cast<float4*>(W0);
        for (int i = tid; i < 64 * 16; i += 256) W04[i] = w04[i];
        const float4* w14 = reinterpret_cast<const float4*>(fW1);
        float4* W14 = reinterpret_cast<float4*>(W1);
        for (int i = tid; i < 64 * 8; i += 256) W14[i] = w14[i];
        if (tid < 32) W2s[tid] = fW2[tid];
        if (tid == 32) W2s[32] = fb2[0];
    }
    const long row0 = (long)blockIdx.x * BR;
    {
        const float4* H4 = reinterpret_cast<const float4*>(h2 + row0 * 64);
        for (int i = tid; i < BR * 16; i += 256) {
            int r = i >> 4, q = i & 15;
            *reinterpret_cast<float4*>(&Hin[r * LDH + q * 4]) = H4[i];
        }
    }
    __syncthreads();

    // ---- fc0: 32x64, tile 2 rows x 4 cols, 256 threads ----
    {
        const int rp = tid >> 4;
        const int cq = tid & 15;
        const int r0 = rp * 2, r1 = r0 + 1;
        const float4 bias = reinterpret_cast<const float4*>(fb0)[cq];
        float4 acc0 = bias, acc1 = bias;
#pragma unroll 2
        for (int k4 = 0; k4 < 64; k4 += 4) {
            const float4 a0 = *reinterpret_cast<const float4*>(&Hin[r0 * LDH + k4]);
            const float4 a1 = *reinterpret_cast<const float4*>(&Hin[r1 * LDH + k4]);
            const float4 w0 = *reinterpret_cast<const float4*>(&W0[(k4 + 0) * 64 + cq * 4]);
            const float4 w1 = *reinterpret_cast<const float4*>(&W0[(k4 + 1) * 64 + cq * 4]);
            const float4 w2 = *reinterpret_cast<const float4*>(&W0[(k4 + 2) * 64 + cq * 4]);
            const float4 w3 = *reinterpret_cast<const float4*>(&W0[(k4 + 3) * 64 + cq * 4]);
            acc0.x = fmaf(a0.x, w0.x, fmaf(a0.y, w1.x, fmaf(a0.z, w2.x, fmaf(a0.w, w3.x, acc0.x))));
            acc0.y = fmaf(a0.x, w0.y, fmaf(a0.y, w1.y, fmaf(a0.z, w2.y, fmaf(a0.w, w3.y, acc0.y))));
            acc0.z = fmaf(a0.x, w0.z, fmaf(a0.y, w1.z, fmaf(a0.z, w2.z, fmaf(a0.w, w3.z, acc0.z))));
            acc0.w = fmaf(a0.x, w0.w, fmaf(a0.y, w1.w, fmaf(a0.z, w2.w, fmaf(a0.w, w3.w, acc0.w))));
            acc1.x = fmaf(a1.x, w0.x, fmaf(a1.y, w1.x, fmaf(a1.z, w2.x, fmaf(a1.w, w3.x, acc1.x))));
            acc1.y = fmaf(a1.x, w0.y, fmaf(a1.y, w1.y, fmaf(a1.z, w2.y, fmaf(a1.w, w3.y, acc1.y))));
            acc1.z = fmaf(a1.x, w0.z, fmaf(a1.y, w1.z, fmaf(a1.z, w2.z, fmaf(a1.w, w3.z, acc1.z))));
            acc1.w = fmaf(a1.x, w0.w, fmaf(a1.y, w1.w, fmaf(a1.z, w2.w, fmaf(a1.w, w3.w, acc1.w))));
        }
        float4 t0, t1;
        t0.x = tanhf(acc0.x); t0.y = tanhf(acc0.y); t0.z = tanhf(acc0.z); t0.w = tanhf(acc0.w);
        t1.x = tanhf(acc1.x); t1.y = tanhf(acc1.y); t1.z = tanhf(acc1.z); t1.w = tanhf(acc1.w);
        *reinterpret_cast<float4*>(&Ht[r0 * LDH + cq * 4]) = t0;
        *reinterpret_cast<float4*>(&Ht[r1 * LDH + cq * 4]) = t1;
    }
    __syncthreads();

    // ---- fc1: 32x32, tile 1 row x 4 cols, 256 threads ----
    {
        const int r = tid >> 3;
        const int cq = tid & 7;
        const float4 bias = reinterpret_cast<const float4*>(fb1)[cq];
        float4 acc0 = bias;
#pragma unroll 2
        for (int k4 = 0; k4 < 64; k4 += 4) {
            const float4 a0 = *reinterpret_cast<const float4*>(&Ht[r * LDH + k4]);
            const float4 w0 = *reinterpret_cast<const float4*>(&W1[(k4 + 0) * 32 + cq * 4]);
            const float4 w1 = *reinterpret_cast<const float4*>(&W1[(k4 + 1) * 32 + cq * 4]);
            const float4 w2 = *reinterpret_cast<const float4*>(&W1[(k4 + 2) * 32 + cq * 4]);
            const float4 w3 = *reinterpret_cast<const float4*>(&W1[(k4 + 3) * 32 + cq * 4]);
            acc0.x = fmaf(a0.x, w0.x, fmaf(a0.y, w1.x, fmaf(a0.z, w2.x, fmaf(a0.w, w3.x, acc0.x))));
            acc0.y = fmaf(a0.x, w0.y, fmaf(a0.y, w1.y, fmaf(a0.z, w2.y, fmaf(a0.w, w3.y, acc0.y))));
            acc0.z = fmaf(a0.x, w0.z, fmaf(a0.y, w1.z, fmaf(a0.z, w2.z, fmaf(a0.w, w3.z, acc0.z))));
            acc0.w = fmaf(a0.x, w0.w, fmaf(a0.y, w1.w, fmaf(a0.z, w2.w, fmaf(a0.w, w3.w, acc0.w))));
        }
        Hs[r * 33 + cq * 4 + 0] = tanhf(acc0.x);
        Hs[r * 33 + cq * 4 + 1] = tanhf(acc0.y);
        Hs[r * 33 + cq * 4 + 2] = tanhf(acc0.z);
        Hs[r * 33 + cq * 4 + 3] = tanhf(acc0.w);
    }
    __syncthreads();

    // ---- fc2: 32 -> 1 ----
    if (tid < BR) {
        float a = W2s[32];
        for (int k = 0; k < 32; ++k) a = fmaf(Hs[tid * 33 + k], W2s[k], a);
        out[row0 + tid] = a;
    }
}

// ---------------- launch ----------------

extern "C" void kernel_launch(void* const* d_in, const int* in_sizes, int n_in,
                              void* d_out, int out_size, void* d_ws, size_t ws_size,
                              hipStream_t stream) {
    const float* x    = (const float*)d_in[0];
    const int*   eidx = (const int*)d_in[1];
    const float* cW0  = (const float*)d_in[2];
    const float* cb0  = (const float*)d_in[3];
    const float* cW1  = (const float*)d_in[4];
    const float* cb1  = (const float*)d_in[5];
    const float* fW0  = (const float*)d_in[6];
    const float* fb0  = (const float*)d_in[7];
    const float* fW1  = (const float*)d_in[8];
    const float* fb1  = (const float*)d_in[9];
    const float* fW2  = (const float*)d_in[10];
    const float* fb2  = (const float*)d_in[11];
    float* out = (float*)d_out;

    const int* src = eidx;
    const int* dst = eidx + N_EDGES;

    char* ws = (char*)d_ws;
    unsigned* rowptr  = (unsigned*)(ws);                  // 400,004 B
    float*    dinv    = (float*)   (ws + 400016);         // 400,000 B
    unsigned* cnt     = (unsigned*)(ws + 800016);         // 391*391*4 = 611,524 B
    unsigned* btot    = (unsigned*)(ws + 1411552);        // 1,564 B
    unsigned* bktbase = (unsigned*)(ws + 1413120);        // 1,568 B
    int*      ssrc    = (int*)     (ws + 1414688);        // 6,400,000 B
    ushort_t* xlb     = (ushort_t*)(ws + 7814688);        // 12,800,000 B
    unsigned* binned  = (unsigned*)(ws + 20614688);       // 6,400,000 B
    float*    bufB    = (float*)   (ws + 27014688);       // 25,600,000 B -> ends 52,614,688

    const int gRow = N_NODES / 32;            // 3125
    const int gAgg = N_NODES / 4;             // 25000

    // CSR build (deterministic, no global fine-grained atomics)
    k_count<<<NBLK_A, 256, 0, stream>>>(dst, cnt);
    k_bucket_scan<<<NB, 512, 0, stream>>>(cnt, btot);
    k_scan_bkt<<<1, 512, 0, stream>>>(btot, bktbase);
    k_bin<<<NBLK_A, 256, 0, stream>>>(src, dst, cnt, bktbase, binned);
    k_csr_fill2<<<NB, 256, 0, stream>>>(binned, bktbase, rowptr, dinv, ssrc);

    // conv0
    k_gemm_bf<128, 64><<<gRow, 256, 0, stream>>>(x, cW0, dinv, xlb);
    k_agg<<<gAgg, 256, 0, stream>>>(xlb, dinv, rowptr, ssrc, cb0, bufB);
    // conv1
    k_gemm_bf<64, 64><<<gRow, 256, 0, stream>>>(bufB, cW1, dinv, xlb);
    k_agg<<<gAgg, 256, 0, stream>>>(xlb, dinv, rowptr, ssrc, cb1, bufB);
    // fc stack
    k_fc<<<gRow, 256, 0, stream>>>(bufB, fW0, fb0, fW1, fb1, fW2, fb2, out);
}

// Round 8
// 270.259 us; speedup vs baseline: 1.5449x; 1.0155x over previous
//
#include <hip/hip_runtime.h>
#include <math.h>

#define N_NODES 100000
#define N_EDGES 1600000
#define NB     391   // buckets of 256 nodes
#define CHUNK  4096  // edges per chunk block
#define NBLK_A 391   // ceil(E/CHUNK)

typedef unsigned short ushort_t;
typedef __attribute__((ext_vector_type(2))) float f2v;

__device__ inline unsigned short f2bf(float f) {
    unsigned u = __float_as_uint(f);
    unsigned r = (u + 0x7FFFu + ((u >> 16) & 1u)) >> 16;
    return (unsigned short)r;
}
// accumulate 2 packed bf16 into a float2 accumulator (v_pk_add_f32)
__device__ inline void accp(f2v& a, unsigned u) {
    f2v t;
    t.x = __uint_as_float(u << 16);
    t.y = __uint_as_float(u & 0xFFFF0000u);
    a += t;
}
// tanh(x) = 1 - 2/(exp(2x)+1); saturates correctly at +-1, err ~1e-6
__device__ inline float fast_tanh(float x) {
    float e = __expf(2.0f * x);
    return fmaf(-2.0f, __builtin_amdgcn_rcpf(e + 1.0f), 1.0f);
}

// ---------------- CSR build: deterministic 3-level multisplit ----------------

__global__ __launch_bounds__(256) void k_count(const int* __restrict__ dst,
                                               unsigned* __restrict__ cnt) {
    __shared__ unsigned h[NB];
    const int tid = threadIdx.x;
    const long e0 = (long)blockIdx.x * CHUNK;
    for (int i = tid; i < NB; i += 256) h[i] = 0u;
    __syncthreads();
    for (int i = tid; i < CHUNK; i += 256) {
        long e = e0 + i;
        if (e < N_EDGES) atomicAdd(&h[((unsigned)dst[e]) >> 8], 1u);
    }
    __syncthreads();
    for (int b = tid; b < NB; b += 256) cnt[b * NBLK_A + blockIdx.x] = h[b];
}

__global__ __launch_bounds__(512) void k_bucket_scan(unsigned* __restrict__ cnt,
                                                     unsigned* __restrict__ btot) {
    __shared__ unsigned s[512];
    const int tid = threadIdx.x;
    const int b = blockIdx.x;
    unsigned v = (tid < NBLK_A) ? cnt[b * NBLK_A + tid] : 0u;
    s[tid] = v;
    __syncthreads();
    for (int o = 1; o < 512; o <<= 1) {
        unsigned t = (tid >= o) ? s[tid - o] : 0u;
        __syncthreads();
        s[tid] += t;
        __syncthreads();
    }
    if (tid < NBLK_A) cnt[b * NBLK_A + tid] = s[tid] - v;   // exclusive within bucket
    if (tid == NBLK_A - 1) btot[b] = s[tid];
}

__global__ __launch_bounds__(512) void k_scan_bkt(const unsigned* __restrict__ btot,
                                                  unsigned* __restrict__ bktbase) {
    __shared__ unsigned s[512];
    const int tid = threadIdx.x;
    unsigned v = (tid < NB) ? btot[tid] : 0u;
    s[tid] = v;
    __syncthreads();
    for (int o = 1; o < 512; o <<= 1) {
        unsigned t = (tid >= o) ? s[tid - o] : 0u;
        __syncthreads();
        s[tid] += t;
        __syncthreads();
    }
    if (tid < NB) bktbase[tid] = s[tid] - v;
    if (tid == NB - 1) bktbase[NB] = s[tid];   // == E
}

// phase A: LDS multisplit into 391 buckets; base from scanned cnt matrix
__global__ __launch_bounds__(256) void k_bin(const int* __restrict__ src,
                                             const int* __restrict__ dst,
                                             const unsigned* __restrict__ cnt,
                                             const unsigned* __restrict__ bktbase,
                                             unsigned* __restrict__ binned) {
    __shared__ unsigned cntA[NB];
    __shared__ unsigned excl[NB];
    __shared__ unsigned gbase[NB];
    __shared__ unsigned scanbuf[512];
    __shared__ unsigned data[CHUNK];
    const int tid = threadIdx.x;
    const long e0 = (long)blockIdx.x * CHUNK;

    for (int i = tid; i < NB; i += 256) cntA[i] = 0u;
    __syncthreads();
    for (int i = tid; i < CHUNK; i += 256) {
        long e = e0 + i;
        if (e < N_EDGES) atomicAdd(&cntA[((unsigned)dst[e]) >> 8], 1u);
    }
    __syncthreads();
    scanbuf[tid] = (tid < NB) ? cntA[tid] : 0u;
    scanbuf[tid + 256] = (tid + 256 < NB) ? cntA[tid + 256] : 0u;
    __syncthreads();
    for (int o = 1; o < 512; o <<= 1) {
        unsigned v0 = (tid >= o) ? scanbuf[tid - o] : 0u;
        unsigned v1 = (tid + 256 >= o) ? scanbuf[tid + 256 - o] : 0u;
        __syncthreads();
        scanbuf[tid] += v0;
        scanbuf[tid + 256] += v1;
        __syncthreads();
    }
    for (int b = tid; b < NB; b += 256) {
        excl[b] = scanbuf[b] - cntA[b];
        gbase[b] = bktbase[b] + cnt[b * NBLK_A + blockIdx.x];
    }
    __syncthreads();
    for (int i = tid; i < NB; i += 256) cntA[i] = 0u;
    __syncthreads();
    for (int i = tid; i < CHUNK; i += 256) {
        long e = e0 + i;
        if (e < N_EDGES) {
            unsigned d = (unsigned)dst[e];
            unsigned b = d >> 8;
            unsigned slot = excl[b] + atomicAdd(&cntA[b], 1u);
            data[slot] = (((unsigned)src[e]) << 8) | (d & 255u);
        }
    }
    __syncthreads();
    const int w = tid >> 6, lane = tid & 63;
    for (int b = w; b < NB; b += 4) {
        unsigned c = cntA[b];
        unsigned sb = excl[b], gb = gbase[b];
        for (unsigned k = lane; k < c; k += 64)
            binned[gb + k] = data[sb + k];
    }
}

// phase B: per-bucket CSR fill; derives degree/rowptr/dinv from binned
__global__ __launch_bounds__(256) void k_csr_fill2(const unsigned* __restrict__ binned,
                                                   const unsigned* __restrict__ bktbase,
                                                   unsigned* __restrict__ rowptr,
                                                   float* __restrict__ dinv,
                                                   int* __restrict__ ssrc) {
    __shared__ unsigned cnt[256];
    __shared__ unsigned s[256];
    __shared__ unsigned cur[256];
    const int b = blockIdx.x;
    const int tid = threadIdx.x;
    const int n0 = b * 256;
    const unsigned beg = bktbase[b], end = bktbase[b + 1];
    cnt[tid] = 0u;
    __syncthreads();
    for (unsigned i = beg + tid; i < end; i += 256)
        atomicAdd(&cnt[binned[i] & 255u], 1u);
    __syncthreads();
    const unsigned v = cnt[tid];
    s[tid] = v;
    __syncthreads();
    for (int o = 1; o < 256; o <<= 1) {
        unsigned t = (tid >= o) ? s[tid - o] : 0u;
        __syncthreads();
        s[tid] += t;
        __syncthreads();
    }
    const unsigned excl = s[tid] - v;
    const int node = n0 + tid;
    if (node < N_NODES) {
        rowptr[node] = beg + excl;
        dinv[node] = rsqrtf((float)(v + 1u));
        if (node == N_NODES - 1) rowptr[N_NODES] = end;   // == E
    }
    cur[tid] = beg + excl;
    __syncthreads();
    for (unsigned i = beg + tid; i < end; i += 256) {
        unsigned p = binned[i];
        unsigned pos = atomicAdd(&cur[p & 255u], 1u);
        ssrc[pos] = (int)(p >> 8);
    }
}

// ---------------- dense layers ----------------

// xlb[N x OUT] (bf16) = (A[N x K] @ W[K x OUT]) * dinv[row]
template<int K, int OUT>
__global__ __launch_bounds__(256) void k_gemm_bf(const float* __restrict__ A,
                                                 const float* __restrict__ W,
                                                 const float* __restrict__ dinv,
                                                 ushort_t* __restrict__ C) {
    constexpr int BR = 32;
    __shared__ float Wld[K * OUT];
    __shared__ float Ald[BR * K];
    const int tid = threadIdx.x;
    for (int i = tid; i < K * OUT; i += 256) Wld[i] = W[i];
    const long row0 = (long)blockIdx.x * BR;
    const float4* A4 = reinterpret_cast<const float4*>(A + row0 * K);
    float4* Ald4w = reinterpret_cast<float4*>(Ald);
    constexpr int NV = BR * K / 4;
    for (int i = tid; i < NV; i += 256) Ald4w[i] = A4[i];
    __syncthreads();

    constexpr int RG = 256 / OUT;
    constexpr int RPT = BR / RG;
    const int col = tid % OUT;
    const int rg = tid / OUT;
    const float4* Ald4 = reinterpret_cast<const float4*>(Ald);
    float acc[RPT];
#pragma unroll
    for (int j = 0; j < RPT; ++j) acc[j] = 0.f;
    for (int k4 = 0; k4 < K; k4 += 4) {
        const float w0 = Wld[(k4 + 0) * OUT + col];
        const float w1 = Wld[(k4 + 1) * OUT + col];
        const float w2 = Wld[(k4 + 2) * OUT + col];
        const float w3 = Wld[(k4 + 3) * OUT + col];
#pragma unroll
        for (int j = 0; j < RPT; ++j) {
            const float4 a = Ald4[((rg + j * RG) * K + k4) >> 2];
            acc[j] = fmaf(a.x, w0, fmaf(a.y, w1, fmaf(a.z, w2, fmaf(a.w, w3, acc[j]))));
        }
    }
#pragma unroll
    for (int j = 0; j < RPT; ++j) {
        const long r = row0 + rg + j * RG;
        C[r * OUT + col] = f2bf(acc[j] * dinv[r]);
    }
}

// one node per 64-lane wave; 4 edge-groups x 16 lanes; lane loads uint2 = 4 bf16.
// packed f32 accumulate; 2-stage reduce; distributed fast_tanh epilogue.
__global__ __launch_bounds__(256) void k_agg(const ushort_t* __restrict__ xlb,
                                             const float* __restrict__ dinv,
                                             const unsigned* __restrict__ rowptr,
                                             const int* __restrict__ ssrc,
                                             const float* __restrict__ bias,
                                             float* __restrict__ h) {
    const int node = blockIdx.x * 4 + (threadIdx.x >> 6);
    const int lane = threadIdx.x & 63;
    const int g = lane >> 4;        // edge group 0..3
    const int l = lane & 15;        // feature quad (features l*4 .. l*4+3)
    const uint2* xb2 = reinterpret_cast<const uint2*>(xlb);  // 16 uint2 per row

    const unsigned beg = rowptr[node], end = rowptr[node + 1];
    f2v a0 = {0.f, 0.f}, a1 = {0.f, 0.f};
    f2v b0 = {0.f, 0.f}, b1 = {0.f, 0.f};
    if (g == 0) {   // self-loop
        const uint2 v = xb2[(size_t)node * 16 + l];
        accp(a0, v.x); accp(a1, v.y);
    }
    unsigned j = beg + g;
    for (; j + 4 < end; j += 8) {
        const int s0i = ssrc[j];
        const int s1i = ssrc[j + 4];
        const uint2 v0 = xb2[(size_t)s0i * 16 + l];
        const uint2 v1 = xb2[(size_t)s1i * 16 + l];
        accp(a0, v0.x); accp(a1, v0.y);
        accp(b0, v1.x); accp(b1, v1.y);
    }
    if (j < end) {
        const uint2 v = xb2[(size_t)ssrc[j] * 16 + l];
        accp(a0, v.x); accp(a1, v.y);
    }
    a0 += b0; a1 += b1;
    float s0 = a0.x, s1 = a0.y, s2 = a1.x, s3 = a1.y;
    s0 += __shfl_xor(s0, 16); s1 += __shfl_xor(s1, 16);
    s2 += __shfl_xor(s2, 16); s3 += __shfl_xor(s3, 16);
    s0 += __shfl_xor(s0, 32); s1 += __shfl_xor(s1, 32);
    s2 += __shfl_xor(s2, 32); s3 += __shfl_xor(s3, 32);
    // each lane finalizes one feature: f = l*4 + g
    const float t01 = (g & 1) ? s1 : s0;
    const float t23 = (g & 1) ? s3 : s2;
    const float v = (g & 2) ? t23 : t01;
    const int f = l * 4 + g;
    const float r = fast_tanh(fmaf(v, dinv[node], bias[f]));
    h[(size_t)node * 64 + f] = r;
}

// fused FC stack, register-tiled fp32 with controlled unrolling + fast_tanh.
__global__ __launch_bounds__(256, 4) void k_fc(const float* __restrict__ h2,
                                               const float* __restrict__ fW0, const float* __restrict__ fb0,
                                               const float* __restrict__ fW1, const float* __restrict__ fb1,
                                               const float* __restrict__ fW2, const float* __restrict__ fb2,
                                               float* __restrict__ out) {
    constexpr int BR = 32;
    constexpr int LDH = 68;
    __shared__ float W0[64 * 64];
    __shared__ float W1[64 * 32];
    __shared__ float Hin[BR * LDH];
    __shared__ float Ht[BR * LDH];
    __shared__ float Hs[BR * 33];
    __shared__ float W2s[33];
    const int tid = threadIdx.x;
    {
        const float4* w04 = reinterpret_cast<const float4*>(fW0);
        float4* W04 = reinterpret_cast<float4*>(W0);
        for (int i = tid; i < 64 * 16; i += 256) W04[i] = w04[i];
        const float4* w14 = reinterpret_cast<const float4*>(fW1);
        float4* W14 = reinterpret_cast<float4*>(W1);
        for (int i = tid; i < 64 * 8; i += 256) W14[i] = w14[i];
        if (tid < 32) W2s[tid] = fW2[tid];
        if (tid == 32) W2s[32] = fb2[0];
    }
    const long row0 = (long)blockIdx.x * BR;
    {
        const float4* H4 = reinterpret_cast<const float4*>(h2 + row0 * 64);
        for (int i = tid; i < BR * 16; i += 256) {
            int r = i >> 4, q = i & 15;
            *reinterpret_cast<float4*>(&Hin[r * LDH + q * 4]) = H4[i];
        }
    }
    __syncthreads();

    // ---- fc0: 32x64, tile 2 rows x 4 cols, 256 threads ----
    {
        const int rp = tid >> 4;
        const int cq = tid & 15;
        const int r0 = rp * 2, r1 = r0 + 1;
        const float4 bias = reinterpret_cast<const float4*>(fb0)[cq];
        float4 acc0 = bias, acc1 = bias;
#pragma unroll 2
        for (int k4 = 0; k4 < 64; k4 += 4) {
            const float4 a0 = *reinterpret_cast<const float4*>(&Hin[r0 * LDH + k4]);
            const float4 a1 = *reinterpret_cast<const float4*>(&Hin[r1 * LDH + k4]);
            const float4 w0 = *reinterpret_cast<const float4*>(&W0[(k4 + 0) * 64 + cq * 4]);
            const float4 w1 = *reinterpret_cast<const float4*>(&W0[(k4 + 1) * 64 + cq * 4]);
            const float4 w2 = *reinterpret_cast<const float4*>(&W0[(k4 + 2) * 64 + cq * 4]);
            const float4 w3 = *reinterpret_cast<const float4*>(&W0[(k4 + 3) * 64 + cq * 4]);
            acc0.x = fmaf(a0.x, w0.x, fmaf(a0.y, w1.x, fmaf(a0.z, w2.x, fmaf(a0.w, w3.x, acc0.x))));
            acc0.y = fmaf(a0.x, w0.y, fmaf(a0.y, w1.y, fmaf(a0.z, w2.y, fmaf(a0.w, w3.y, acc0.y))));
            acc0.z = fmaf(a0.x, w0.z, fmaf(a0.y, w1.z, fmaf(a0.z, w2.z, fmaf(a0.w, w3.z, acc0.z))));
            acc0.w = fmaf(a0.x, w0.w, fmaf(a0.y, w1.w, fmaf(a0.z, w2.w, fmaf(a0.w, w3.w, acc0.w))));
            acc1.x = fmaf(a1.x, w0.x, fmaf(a1.y, w1.x, fmaf(a1.z, w2.x, fmaf(a1.w, w3.x, acc1.x))));
            acc1.y = fmaf(a1.x, w0.y, fmaf(a1.y, w1.y, fmaf(a1.z, w2.y, fmaf(a1.w, w3.y, acc1.y))));
            acc1.z = fmaf(a1.x, w0.z, fmaf(a1.y, w1.z, fmaf(a1.z, w2.z, fmaf(a1.w, w3.z, acc1.z))));
            acc1.w = fmaf(a1.x, w0.w, fmaf(a1.y, w1.w, fmaf(a1.z, w2.w, fmaf(a1.w, w3.w, acc1.w))));
        }
        float4 t0, t1;
        t0.x = fast_tanh(acc0.x); t0.y = fast_tanh(acc0.y);
        t0.z = fast_tanh(acc0.z); t0.w = fast_tanh(acc0.w);
        t1.x = fast_tanh(acc1.x); t1.y = fast_tanh(acc1.y);
        t1.z = fast_tanh(acc1.z); t1.w = fast_tanh(acc1.w);
        *reinterpret_cast<float4*>(&Ht[r0 * LDH + cq * 4]) = t0;
        *reinterpret_cast<float4*>(&Ht[r1 * LDH + cq * 4]) = t1;
    }
    __syncthreads();

    // ---- fc1: 32x32, tile 1 row x 4 cols, 256 threads ----
    {
        const int r = tid >> 3;
        const int cq = tid & 7;
        const float4 bias = reinterpret_cast<const float4*>(fb1)[cq];
        float4 acc0 = bias;
#pragma unroll 2
        for (int k4 = 0; k4 < 64; k4 += 4) {
            const float4 a0 = *reinterpret_cast<const float4*>(&Ht[r * LDH + k4]);
            const float4 w0 = *reinterpret_cast<const float4*>(&W1[(k4 + 0) * 32 + cq * 4]);
            const float4 w1 = *reinterpret_cast<const float4*>(&W1[(k4 + 1) * 32 + cq * 4]);
            const float4 w2 = *reinterpret_cast<const float4*>(&W1[(k4 + 2) * 32 + cq * 4]);
            const float4 w3 = *reinterpret_cast<const float4*>(&W1[(k4 + 3) * 32 + cq * 4]);
            acc0.x = fmaf(a0.x, w0.x, fmaf(a0.y, w1.x, fmaf(a0.z, w2.x, fmaf(a0.w, w3.x, acc0.x))));
            acc0.y = fmaf(a0.x, w0.y, fmaf(a0.y, w1.y, fmaf(a0.z, w2.y, fmaf(a0.w, w3.y, acc0.y))));
            acc0.z = fmaf(a0.x, w0.z, fmaf(a0.y, w1.z, fmaf(a0.z, w2.z, fmaf(a0.w, w3.z, acc0.z))));
            acc0.w = fmaf(a0.x, w0.w, fmaf(a0.y, w1.w, fmaf(a0.z, w2.w, fmaf(a0.w, w3.w, acc0.w))));
        }
        Hs[r * 33 + cq * 4 + 0] = fast_tanh(acc0.x);
        Hs[r * 33 + cq * 4 + 1] = fast_tanh(acc0.y);
        Hs[r * 33 + cq * 4 + 2] = fast_tanh(acc0.z);
        Hs[r * 33 + cq * 4 + 3] = fast_tanh(acc0.w);
    }
    __syncthreads();

    // ---- fc2: 32 -> 1 ----
    if (tid < BR) {
        float a = W2s[32];
        for (int k = 0; k < 32; ++k) a = fmaf(Hs[tid * 33 + k], W2s[k], a);
        out[row0 + tid] = a;
    }
}

// ---------------- launch ----------------

extern "C" void kernel_launch(void* const* d_in, const int* in_sizes, int n_in,
                              void* d_out, int out_size, void* d_ws, size_t ws_size,
                              hipStream_t stream) {
    const float* x    = (const float*)d_in[0];
    const int*   eidx = (const int*)d_in[1];
    const float* cW0  = (const float*)d_in[2];
    const float* cb0  = (const float*)d_in[3];
    const float* cW1  = (const float*)d_in[4];
    const float* cb1  = (const float*)d_in[5];
    const float* fW0  = (const float*)d_in[6];
    const float* fb0  = (const float*)d_in[7];
    const float* fW1  = (const float*)d_in[8];
    const float* fb1  = (const float*)d_in[9];
    const float* fW2  = (const float*)d_in[10];
    const float* fb2  = (const float*)d_in[11];
    float* out = (float*)d_out;

    const int* src = eidx;
    const int* dst = eidx + N_EDGES;

    char* ws = (char*)d_ws;
    unsigned* rowptr  = (unsigned*)(ws);                  // 400,004 B
    float*    dinv    = (float*)   (ws + 400016);         // 400,000 B
    unsigned* cnt     = (unsigned*)(ws + 800016);         // 611,524 B
    unsigned* btot    = (unsigned*)(ws + 1411552);        // 1,564 B
    unsigned* bktbase = (unsigned*)(ws + 1413120);        // 1,568 B
    int*      ssrc    = (int*)     (ws + 1414688);        // 6,400,000 B
    ushort_t* xlb     = (ushort_t*)(ws + 7814688);        // 12,800,000 B
    unsigned* binned  = (unsigned*)(ws + 20614688);       // 6,400,000 B
    float*    bufB    = (float*)   (ws + 27014688);       // 25,600,000 B -> ends 52,614,688

    const int gRow = N_NODES / 32;            // 3125
    const int gAgg = N_NODES / 4;             // 25000

    // CSR build (deterministic, no global fine-grained atomics)
    k_count<<<NBLK_A, 256, 0, stream>>>(dst, cnt);
    k_bucket_scan<<<NB, 512, 0, stream>>>(cnt, btot);
    k_scan_bkt<<<1, 512, 0, stream>>>(btot, bktbase);
    k_bin<<<NBLK_A, 256, 0, stream>>>(src, dst, cnt, bktbase, binned);
    k_csr_fill2<<<NB, 256, 0, stream>>>(binned, bktbase, rowptr, dinv, ssrc);

    // conv0
    k_gemm_bf<128, 64><<<gRow, 256, 0, stream>>>(x, cW0, dinv, xlb);
    k_agg<<<gAgg, 256, 0, stream>>>(xlb, dinv, rowptr, ssrc, cb0, bufB);
    // conv1
    k_gemm_bf<64, 64><<<gRow, 256, 0, stream>>>(bufB, cW1, dinv, xlb);
    k_agg<<<gAgg, 256, 0, stream>>>(xlb, dinv, rowptr, ssrc, cb1, bufB);
    // fc stack
    k_fc<<<gRow, 256, 0, stream>>>(bufB, fW0, fb0, fW1, fb1, fW2, fb2, out);
}

// Round 9
// 256.184 us; speedup vs baseline: 1.6298x; 1.0549x over previous
//
#include <hip/hip_runtime.h>
#include <math.h>

#define N_NODES 100000
#define N_EDGES 1600000
#define NB     391   // buckets of 256 nodes
#define CHUNK  4096  // edges per chunk block
#define NBLK_A 391   // ceil(E/CHUNK)

typedef unsigned short ushort_t;
typedef __attribute__((ext_vector_type(2))) float f2v;

__device__ inline unsigned short f2bf(float f) {
    unsigned u = __float_as_uint(f);
    unsigned r = (u + 0x7FFFu + ((u >> 16) & 1u)) >> 16;
    return (unsigned short)r;
}
// accumulate 2 packed bf16 into a float2 accumulator (v_pk_add_f32)
__device__ inline void accp(f2v& a, unsigned u) {
    f2v t;
    t.x = __uint_as_float(u << 16);
    t.y = __uint_as_float(u & 0xFFFF0000u);
    a += t;
}
// tanh(x) = 1 - 2/(exp(2x)+1); saturates correctly at +-1, err ~1e-6
__device__ inline float fast_tanh(float x) {
    float e = __expf(2.0f * x);
    return fmaf(-2.0f, __builtin_amdgcn_rcpf(e + 1.0f), 1.0f);
}
// acc += a.x*w0 + a.y*w1 + a.z*w2 + a.w*w3 (component-wise over 4 cols)
__device__ inline void fma4(float4& acc, const float4 a,
                            const float4 w0, const float4 w1,
                            const float4 w2, const float4 w3) {
    acc.x = fmaf(a.x, w0.x, fmaf(a.y, w1.x, fmaf(a.z, w2.x, fmaf(a.w, w3.x, acc.x))));
    acc.y = fmaf(a.x, w0.y, fmaf(a.y, w1.y, fmaf(a.z, w2.y, fmaf(a.w, w3.y, acc.y))));
    acc.z = fmaf(a.x, w0.z, fmaf(a.y, w1.z, fmaf(a.z, w2.z, fmaf(a.w, w3.z, acc.z))));
    acc.w = fmaf(a.x, w0.w, fmaf(a.y, w1.w, fmaf(a.z, w2.w, fmaf(a.w, w3.w, acc.w))));
}

// ---------------- CSR build: deterministic 3-level multisplit ----------------

__global__ __launch_bounds__(256) void k_count(const int* __restrict__ dst,
                                               unsigned* __restrict__ cnt) {
    __shared__ unsigned h[NB];
    const int tid = threadIdx.x;
    const long e0 = (long)blockIdx.x * CHUNK;
    for (int i = tid; i < NB; i += 256) h[i] = 0u;
    __syncthreads();
    for (int i = tid; i < CHUNK; i += 256) {
        long e = e0 + i;
        if (e < N_EDGES) atomicAdd(&h[((unsigned)dst[e]) >> 8], 1u);
    }
    __syncthreads();
    for (int b = tid; b < NB; b += 256) cnt[b * NBLK_A + blockIdx.x] = h[b];
}

__global__ __launch_bounds__(512) void k_bucket_scan(unsigned* __restrict__ cnt,
                                                     unsigned* __restrict__ btot) {
    __shared__ unsigned s[512];
    const int tid = threadIdx.x;
    const int b = blockIdx.x;
    unsigned v = (tid < NBLK_A) ? cnt[b * NBLK_A + tid] : 0u;
    s[tid] = v;
    __syncthreads();
    for (int o = 1; o < 512; o <<= 1) {
        unsigned t = (tid >= o) ? s[tid - o] : 0u;
        __syncthreads();
        s[tid] += t;
        __syncthreads();
    }
    if (tid < NBLK_A) cnt[b * NBLK_A + tid] = s[tid] - v;   // exclusive within bucket
    if (tid == NBLK_A - 1) btot[b] = s[tid];
}

__global__ __launch_bounds__(512) void k_scan_bkt(const unsigned* __restrict__ btot,
                                                  unsigned* __restrict__ bktbase) {
    __shared__ unsigned s[512];
    const int tid = threadIdx.x;
    unsigned v = (tid < NB) ? btot[tid] : 0u;
    s[tid] = v;
    __syncthreads();
    for (int o = 1; o < 512; o <<= 1) {
        unsigned t = (tid >= o) ? s[tid - o] : 0u;
        __syncthreads();
        s[tid] += t;
        __syncthreads();
    }
    if (tid < NB) bktbase[tid] = s[tid] - v;
    if (tid == NB - 1) bktbase[NB] = s[tid];   // == E
}

// phase A: LDS multisplit into 391 buckets; base from scanned cnt matrix
__global__ __launch_bounds__(256) void k_bin(const int* __restrict__ src,
                                             const int* __restrict__ dst,
                                             const unsigned* __restrict__ cnt,
                                             const unsigned* __restrict__ bktbase,
                                             unsigned* __restrict__ binned) {
    __shared__ unsigned cntA[NB];
    __shared__ unsigned excl[NB];
    __shared__ unsigned gbase[NB];
    __shared__ unsigned scanbuf[512];
    __shared__ unsigned data[CHUNK];
    const int tid = threadIdx.x;
    const long e0 = (long)blockIdx.x * CHUNK;

    for (int i = tid; i < NB; i += 256) cntA[i] = 0u;
    __syncthreads();
    for (int i = tid; i < CHUNK; i += 256) {
        long e = e0 + i;
        if (e < N_EDGES) atomicAdd(&cntA[((unsigned)dst[e]) >> 8], 1u);
    }
    __syncthreads();
    scanbuf[tid] = (tid < NB) ? cntA[tid] : 0u;
    scanbuf[tid + 256] = (tid + 256 < NB) ? cntA[tid + 256] : 0u;
    __syncthreads();
    for (int o = 1; o < 512; o <<= 1) {
        unsigned v0 = (tid >= o) ? scanbuf[tid - o] : 0u;
        unsigned v1 = (tid + 256 >= o) ? scanbuf[tid + 256 - o] : 0u;
        __syncthreads();
        scanbuf[tid] += v0;
        scanbuf[tid + 256] += v1;
        __syncthreads();
    }
    for (int b = tid; b < NB; b += 256) {
        excl[b] = scanbuf[b] - cntA[b];
        gbase[b] = bktbase[b] + cnt[b * NBLK_A + blockIdx.x];
    }
    __syncthreads();
    for (int i = tid; i < NB; i += 256) cntA[i] = 0u;
    __syncthreads();
    for (int i = tid; i < CHUNK; i += 256) {
        long e = e0 + i;
        if (e < N_EDGES) {
            unsigned d = (unsigned)dst[e];
            unsigned b = d >> 8;
            unsigned slot = excl[b] + atomicAdd(&cntA[b], 1u);
            data[slot] = (((unsigned)src[e]) << 8) | (d & 255u);
        }
    }
    __syncthreads();
    const int w = tid >> 6, lane = tid & 63;
    for (int b = w; b < NB; b += 4) {
        unsigned c = cntA[b];
        unsigned sb = excl[b], gb = gbase[b];
        for (unsigned k = lane; k < c; k += 64)
            binned[gb + k] = data[sb + k];
    }
}

// phase B: per-bucket CSR fill; derives degree/rowptr/dinv from binned
__global__ __launch_bounds__(256) void k_csr_fill2(const unsigned* __restrict__ binned,
                                                   const unsigned* __restrict__ bktbase,
                                                   unsigned* __restrict__ rowptr,
                                                   float* __restrict__ dinv,
                                                   int* __restrict__ ssrc) {
    __shared__ unsigned cnt[256];
    __shared__ unsigned s[256];
    __shared__ unsigned cur[256];
    const int b = blockIdx.x;
    const int tid = threadIdx.x;
    const int n0 = b * 256;
    const unsigned beg = bktbase[b], end = bktbase[b + 1];
    cnt[tid] = 0u;
    __syncthreads();
    for (unsigned i = beg + tid; i < end; i += 256)
        atomicAdd(&cnt[binned[i] & 255u], 1u);
    __syncthreads();
    const unsigned v = cnt[tid];
    s[tid] = v;
    __syncthreads();
    for (int o = 1; o < 256; o <<= 1) {
        unsigned t = (tid >= o) ? s[tid - o] : 0u;
        __syncthreads();
        s[tid] += t;
        __syncthreads();
    }
    const unsigned excl = s[tid] - v;
    const int node = n0 + tid;
    if (node < N_NODES) {
        rowptr[node] = beg + excl;
        dinv[node] = rsqrtf((float)(v + 1u));
        if (node == N_NODES - 1) rowptr[N_NODES] = end;   // == E
    }
    cur[tid] = beg + excl;
    __syncthreads();
    for (unsigned i = beg + tid; i < end; i += 256) {
        unsigned p = binned[i];
        unsigned pos = atomicAdd(&cur[p & 255u], 1u);
        ssrc[pos] = (int)(p >> 8);
    }
}

// ---------------- dense layers ----------------

// xlb[N x 64] (bf16) = (A[N x K] @ W[K x 64]) * dinv[row]
// 64 rows x 64 cols per 256-thread block; 4x4 register tile per thread.
// Per k4: 8 ds_read_b128 per 64 FMAs. W row-major [k][64]; A staged stride K+4.
template<int K>
__global__ __launch_bounds__(256) void k_gemm_bf(const float* __restrict__ A,
                                                 const float* __restrict__ W,
                                                 const float* __restrict__ dinv,
                                                 ushort_t* __restrict__ C) {
    constexpr int OUT = 64;
    constexpr int BR = 64;
    constexpr int LDA = K + 4;
    __shared__ float Wld[K * OUT];
    __shared__ float Ald[BR * LDA];
    const int tid = threadIdx.x;
    const int row0 = blockIdx.x * BR;
    const int nrows = (N_NODES - row0 < BR) ? (N_NODES - row0) : BR;

    {
        const float4* W4 = reinterpret_cast<const float4*>(W);
        float4* Wl4 = reinterpret_cast<float4*>(Wld);
        for (int i = tid; i < K * OUT / 4; i += 256) Wl4[i] = W4[i];
        const float4* A4 = reinterpret_cast<const float4*>(A + (size_t)row0 * K);
        const int nv = nrows * (K / 4);
        for (int i = tid; i < nv; i += 256) {
            int r = i / (K / 4), q = i % (K / 4);
            *reinterpret_cast<float4*>(&Ald[r * LDA + q * 4]) = A4[i];
        }
    }
    __syncthreads();

    const int tr = tid >> 4;        // row tile 0..15
    const int tc = tid & 15;        // col tile 0..15
    const int r0 = tr * 4;
    float4 acc0 = {0,0,0,0}, acc1 = {0,0,0,0}, acc2 = {0,0,0,0}, acc3 = {0,0,0,0};
#pragma unroll 2
    for (int k4 = 0; k4 < K; k4 += 4) {
        const float4 a0 = *reinterpret_cast<const float4*>(&Ald[(r0 + 0) * LDA + k4]);
        const float4 a1 = *reinterpret_cast<const float4*>(&Ald[(r0 + 1) * LDA + k4]);
        const float4 a2 = *reinterpret_cast<const float4*>(&Ald[(r0 + 2) * LDA + k4]);
        const float4 a3 = *reinterpret_cast<const float4*>(&Ald[(r0 + 3) * LDA + k4]);
        const float4 w0 = *reinterpret_cast<const float4*>(&Wld[(k4 + 0) * OUT + tc * 4]);
        const float4 w1 = *reinterpret_cast<const float4*>(&Wld[(k4 + 1) * OUT + tc * 4]);
        const float4 w2 = *reinterpret_cast<const float4*>(&Wld[(k4 + 2) * OUT + tc * 4]);
        const float4 w3 = *reinterpret_cast<const float4*>(&Wld[(k4 + 3) * OUT + tc * 4]);
        fma4(acc0, a0, w0, w1, w2, w3);
        fma4(acc1, a1, w0, w1, w2, w3);
        fma4(acc2, a2, w0, w1, w2, w3);
        fma4(acc3, a3, w0, w1, w2, w3);
    }
    float4 accs[4] = {acc0, acc1, acc2, acc3};
#pragma unroll
    for (int i = 0; i < 4; ++i) {
        const int r = r0 + i;
        if (r < nrows) {
            const float di = dinv[row0 + r];
            ushort4 o;
            o.x = f2bf(accs[i].x * di);
            o.y = f2bf(accs[i].y * di);
            o.z = f2bf(accs[i].z * di);
            o.w = f2bf(accs[i].w * di);
            *reinterpret_cast<ushort4*>(&C[(size_t)(row0 + r) * OUT + tc * 4]) = o;
        }
    }
}

// one node per 64-lane wave; 4 edge-groups x 16 lanes; lane loads uint2 = 4 bf16.
// 16 gathers in flight per wave (4 groups x unroll 4).
__global__ __launch_bounds__(256) void k_agg(const ushort_t* __restrict__ xlb,
                                             const float* __restrict__ dinv,
                                             const unsigned* __restrict__ rowptr,
                                             const int* __restrict__ ssrc,
                                             const float* __restrict__ bias,
                                             float* __restrict__ h) {
    const int node = blockIdx.x * 4 + (threadIdx.x >> 6);
    const int lane = threadIdx.x & 63;
    const int g = lane >> 4;        // edge group 0..3
    const int l = lane & 15;        // feature quad
    const uint2* xb2 = reinterpret_cast<const uint2*>(xlb);  // 16 uint2 per row

    const unsigned beg = rowptr[node], end = rowptr[node + 1];
    f2v a0 = {0.f, 0.f}, a1 = {0.f, 0.f};
    f2v b0 = {0.f, 0.f}, b1 = {0.f, 0.f};
    if (g == 0) {   // self-loop
        const uint2 v = xb2[(size_t)node * 16 + l];
        accp(a0, v.x); accp(a1, v.y);
    }
    unsigned j = beg + g;
    for (; j + 12 < end; j += 16) {
        const int s0i = ssrc[j];
        const int s1i = ssrc[j + 4];
        const int s2i = ssrc[j + 8];
        const int s3i = ssrc[j + 12];
        const uint2 v0 = xb2[(size_t)s0i * 16 + l];
        const uint2 v1 = xb2[(size_t)s1i * 16 + l];
        const uint2 v2 = xb2[(size_t)s2i * 16 + l];
        const uint2 v3 = xb2[(size_t)s3i * 16 + l];
        accp(a0, v0.x); accp(a1, v0.y);
        accp(b0, v1.x); accp(b1, v1.y);
        accp(a0, v2.x); accp(a1, v2.y);
        accp(b0, v3.x); accp(b1, v3.y);
    }
    for (; j < end; j += 4) {
        const uint2 v = xb2[(size_t)ssrc[j] * 16 + l];
        accp(a0, v.x); accp(a1, v.y);
    }
    a0 += b0; a1 += b1;
    float s0 = a0.x, s1 = a0.y, s2 = a1.x, s3 = a1.y;
    s0 += __shfl_xor(s0, 16); s1 += __shfl_xor(s1, 16);
    s2 += __shfl_xor(s2, 16); s3 += __shfl_xor(s3, 16);
    s0 += __shfl_xor(s0, 32); s1 += __shfl_xor(s1, 32);
    s2 += __shfl_xor(s2, 32); s3 += __shfl_xor(s3, 32);
    // each lane finalizes one feature: f = l*4 + g
    const float t01 = (g & 1) ? s1 : s0;
    const float t23 = (g & 1) ? s3 : s2;
    const float v = (g & 2) ? t23 : t01;
    const int f = l * 4 + g;
    const float r = fast_tanh(fmaf(v, dinv[node], bias[f]));
    h[(size_t)node * 64 + f] = r;
}

// fused FC stack, register-tiled fp32 with controlled unrolling + fast_tanh.
__global__ __launch_bounds__(256, 4) void k_fc(const float* __restrict__ h2,
                                               const float* __restrict__ fW0, const float* __restrict__ fb0,
                                               const float* __restrict__ fW1, const float* __restrict__ fb1,
                                               const float* __restrict__ fW2, const float* __restrict__ fb2,
                                               float* __restrict__ out) {
    constexpr int BR = 32;
    constexpr int LDH = 68;
    __shared__ float W0[64 * 64];
    __shared__ float W1[64 * 32];
    __shared__ float Hin[BR * LDH];
    __shared__ float Ht[BR * LDH];
    __shared__ float Hs[BR * 33];
    __shared__ float W2s[33];
    const int tid = threadIdx.x;
    {
        const float4* w04 = reinterpret_cast<const float4*>(fW0);
        float4* W04 = reinterpret_cast<float4*>(W0);
        for (int i = tid; i < 64 * 16; i += 256) W04[i] = w04[i];
        const float4* w14 = reinterpret_cast<const float4*>(fW1);
        float4* W14 = reinterpret_cast<float4*>(W1);
        for (int i = tid; i < 64 * 8; i += 256) W14[i] = w14[i];
        if (tid < 32) W2s[tid] = fW2[tid];
        if (tid == 32) W2s[32] = fb2[0];
    }
    const long row0 = (long)blockIdx.x * BR;
    {
        const float4* H4 = reinterpret_cast<const float4*>(h2 + row0 * 64);
        for (int i = tid; i < BR * 16; i += 256) {
            int r = i >> 4, q = i & 15;
            *reinterpret_cast<float4*>(&Hin[r * LDH + q * 4]) = H4[i];
        }
    }
    __syncthreads();

    // ---- fc0: 32x64, tile 2 rows x 4 cols, 256 threads ----
    {
        const int rp = tid >> 4;
        const int cq = tid & 15;
        const int r0 = rp * 2, r1 = r0 + 1;
        const float4 bias = reinterpret_cast<const float4*>(fb0)[cq];
        float4 acc0 = bias, acc1 = bias;
#pragma unroll 2
        for (int k4 = 0; k4 < 64; k4 += 4) {
            const float4 a0 = *reinterpret_cast<const float4*>(&Hin[r0 * LDH + k4]);
            const float4 a1 = *reinterpret_cast<const float4*>(&Hin[r1 * LDH + k4]);
            const float4 w0 = *reinterpret_cast<const float4*>(&W0[(k4 + 0) * 64 + cq * 4]);
            const float4 w1 = *reinterpret_cast<const float4*>(&W0[(k4 + 1) * 64 + cq * 4]);
            const float4 w2 = *reinterpret_cast<const float4*>(&W0[(k4 + 2) * 64 + cq * 4]);
            const float4 w3 = *reinterpret_cast<const float4*>(&W0[(k4 + 3) * 64 + cq * 4]);
            fma4(acc0, a0, w0, w1, w2, w3);
            fma4(acc1, a1, w0, w1, w2, w3);
        }
        float4 t0, t1;
        t0.x = fast_tanh(acc0.x); t0.y = fast_tanh(acc0.y);
        t0.z = fast_tanh(acc0.z); t0.w = fast_tanh(acc0.w);
        t1.x = fast_tanh(acc1.x); t1.y = fast_tanh(acc1.y);
        t1.z = fast_tanh(acc1.z); t1.w = fast_tanh(acc1.w);
        *reinterpret_cast<float4*>(&Ht[r0 * LDH + cq * 4]) = t0;
        *reinterpret_cast<float4*>(&Ht[r1 * LDH + cq * 4]) = t1;
    }
    __syncthreads();

    // ---- fc1: 32x32, tile 1 row x 4 cols, 256 threads ----
    {
        const int r = tid >> 3;
        const int cq = tid & 7;
        const float4 bias = reinterpret_cast<const float4*>(fb1)[cq];
        float4 acc0 = bias;
#pragma unroll 2
        for (int k4 = 0; k4 < 64; k4 += 4) {
            const float4 a0 = *reinterpret_cast<const float4*>(&Ht[r * LDH + k4]);
            const float4 w0 = *reinterpret_cast<const float4*>(&W1[(k4 + 0) * 32 + cq * 4]);
            const float4 w1 = *reinterpret_cast<const float4*>(&W1[(k4 + 1) * 32 + cq * 4]);
            const float4 w2 = *reinterpret_cast<const float4*>(&W1[(k4 + 2) * 32 + cq * 4]);
            const float4 w3 = *reinterpret_cast<const float4*>(&W1[(k4 + 3) * 32 + cq * 4]);
            fma4(acc0, a0, w0, w1, w2, w3);
        }
        Hs[r * 33 + cq * 4 + 0] = fast_tanh(acc0.x);
        Hs[r * 33 + cq * 4 + 1] = fast_tanh(acc0.y);
        Hs[r * 33 + cq * 4 + 2] = fast_tanh(acc0.z);
        Hs[r * 33 + cq * 4 + 3] = fast_tanh(acc0.w);
    }
    __syncthreads();

    // ---- fc2: 32 -> 1 ----
    if (tid < BR) {
        float a = W2s[32];
        for (int k = 0; k < 32; ++k) a = fmaf(Hs[tid * 33 + k], W2s[k], a);
        out[row0 + tid] = a;
    }
}

// ---------------- launch ----------------

extern "C" void kernel_launch(void* const* d_in, const int* in_sizes, int n_in,
                              void* d_out, int out_size, void* d_ws, size_t ws_size,
                              hipStream_t stream) {
    const float* x    = (const float*)d_in[0];
    const int*   eidx = (const int*)d_in[1];
    const float* cW0  = (const float*)d_in[2];
    const float* cb0  = (const float*)d_in[3];
    const float* cW1  = (const float*)d_in[4];
    const float* cb1  = (const float*)d_in[5];
    const float* fW0  = (const float*)d_in[6];
    const float* fb0  = (const float*)d_in[7];
    const float* fW1  = (const float*)d_in[8];
    const float* fb1  = (const float*)d_in[9];
    const float* fW2  = (const float*)d_in[10];
    const float* fb2  = (const float*)d_in[11];
    float* out = (float*)d_out;

    const int* src = eidx;
    const int* dst = eidx + N_EDGES;

    char* ws = (char*)d_ws;
    unsigned* rowptr  = (unsigned*)(ws);                  // 400,004 B
    float*    dinv    = (float*)   (ws + 400016);         // 400,000 B
    unsigned* cnt     = (unsigned*)(ws + 800016);         // 611,524 B
    unsigned* btot    = (unsigned*)(ws + 1411552);        // 1,564 B
    unsigned* bktbase = (unsigned*)(ws + 1413120);        // 1,568 B
    int*      ssrc    = (int*)     (ws + 1414688);        // 6,400,000 B
    ushort_t* xlb     = (ushort_t*)(ws + 7814688);        // 12,800,000 B
    unsigned* binned  = (unsigned*)(ws + 20614688);       // 6,400,000 B
    float*    bufB    = (float*)   (ws + 27014688);       // 25,600,000 B -> ends 52,614,688

    const int gRow = N_NODES / 32;              // 3125 (k_fc)
    const int gGemm = (N_NODES + 63) / 64;      // 1563
    const int gAgg = N_NODES / 4;               // 25000

    // CSR build (deterministic, no global fine-grained atomics)
    k_count<<<NBLK_A, 256, 0, stream>>>(dst, cnt);
    k_bucket_scan<<<NB, 512, 0, stream>>>(cnt, btot);
    k_scan_bkt<<<1, 512, 0, stream>>>(btot, bktbase);
    k_bin<<<NBLK_A, 256, 0, stream>>>(src, dst, cnt, bktbase, binned);
    k_csr_fill2<<<NB, 256, 0, stream>>>(binned, bktbase, rowptr, dinv, ssrc);

    // conv0
    k_gemm_bf<128><<<gGemm, 256, 0, stream>>>(x, cW0, dinv, xlb);
    k_agg<<<gAgg, 256, 0, stream>>>(xlb, dinv, rowptr, ssrc, cb0, bufB);
    // conv1
    k_gemm_bf<64><<<gGemm, 256, 0, stream>>>(bufB, cW1, dinv, xlb);
    k_agg<<<gAgg, 256, 0, stream>>>(xlb, dinv, rowptr, ssrc, cb1, bufB);
    // fc stack
    k_fc<<<gRow, 256, 0, stream>>>(bufB, fW0, fb0, fW1, fb1, fW2, fb2, out);
}